// Round 12
// baseline (80.151 us; speedup 1.0000x reference)
//
#include <hip/hip_runtime.h>

typedef short bf16x8 __attribute__((ext_vector_type(8)));
typedef float f32x4 __attribute__((ext_vector_type(4)));
typedef ushort ushort8 __attribute__((ext_vector_type(8)));

#define DIM 1024
#define MAXSLOT 4096
#define PREP_TBLKS 1088   // transpose blocks in prep kernel (wg/wu, split x2)

__device__ __forceinline__ ushort f2bf(float f) {
  unsigned u = __float_as_uint(f);
  u += 0x7fffu + ((u >> 16) & 1u);   // round-to-nearest-even
  return (ushort)(u >> 16);
}

__device__ __forceinline__ void gld16(const ushort* g, ushort* l) {
  __builtin_amdgcn_global_load_lds(
      (const __attribute__((address_space(1))) unsigned int*)g,
      (__attribute__((address_space(3))) unsigned int*)l, 16, 0, 0);
}

// ---------------------------------------------------------------------------
// Transpose a sub-range of one 64-row slab of fp32 [K][C] into tiled bf16
// T[C/64][K/64][64][64] (tile [n_local][k_local], 8KB contiguous per tile).
// bf16-PAIR-PACKED LDS tile (8.3KB/buf, dbuf -> full wave occupancy).
// ---------------------------------------------------------------------------
__device__ __forceinline__ void transpose_slab(
    const float* __restrict__ src, ushort* __restrict__ dst,
    int K, int C, int kb, int nb0, int nbcnt, uint* tile0, uint* tile1) {
  int k0 = kb << 6;
  int tid = threadIdx.x;
  int tx = tid & 15, ty = tid >> 4;   // load: cols 4tx.., pair-rows {ty, 16+ty}
  int sx = tid & 7,  sy = tid >> 3;   // store: out rows {sy, 32+sy}, ks 8sx..
  int kt = K >> 6;
  uint* bufs[2] = {tile0, tile1};
  float4 v[4];                        // [p*2+q]: row 2*(p*16+ty)+q

  auto loadT = [&](int nb) {
#pragma unroll
    for (int p = 0; p < 2; ++p)
#pragma unroll
      for (int q = 0; q < 2; ++q)
        v[p * 2 + q] = *(const float4*)(
            src + (size_t)(k0 + (p * 16 + ty) * 2 + q) * C + (nb << 6) + tx * 4);
  };
  auto packW = [&](uint* buf) {
#pragma unroll
    for (int p = 0; p < 2; ++p) {
      uint u[4];
#pragma unroll
      for (int c = 0; c < 4; ++c) {
        float lo = ((const float*)&v[p * 2])[c];
        float hi = ((const float*)&v[p * 2 + 1])[c];
        u[c] = (uint)f2bf(lo) | ((uint)f2bf(hi) << 16);
      }
      *(uint4*)&buf[(p * 16 + ty) * 65 + tx * 4] = *(uint4*)u;
    }
  };

  loadT(nb0); packW(bufs[0]);
  __syncthreads();
  for (int i = 0; i < nbcnt; ++i) {
    bool more = i + 1 < nbcnt;
    if (more) loadT(nb0 + i + 1);
    uint* cur = bufs[i & 1];
    ushort* tb = dst + ((size_t)(nb0 + i) * kt + kb) * 4096;
#pragma unroll
    for (int p = 0; p < 2; ++p) {
      int n = p * 32 + sy;
      ushort8 o;
#pragma unroll
      for (int jj = 0; jj < 4; ++jj) {
        uint u = cur[(4 * sx + jj) * 65 + n];
        o[2 * jj]     = (ushort)(u & 0xffff);
        o[2 * jj + 1] = (ushort)(u >> 16);
      }
      *(ushort8*)(tb + n * 64 + sx * 8) = o;
    }
    if (more) packW(bufs[(i + 1) & 1]);
    __syncthreads();
  }
}

// meta layout (ints): [16..23] base_text; [25..32] base_vis; [34] ntiles_text;
// [35] ntiles_vis; [40..71] tile_expert_text; [72..103] tile_expert_vis.

// ---------------------------------------------------------------------------
// Fused: blocks [0,1088): wg/wu transpose half-slabs. blocks [1088,1344): router.
// ---------------------------------------------------------------------------
__global__ __launch_bounds__(256) void prep_router_kernel(
    const float* __restrict__ s_wg, const float* __restrict__ s_wu,
    const float* __restrict__ t_wg, const float* __restrict__ t_wu,
    const float* __restrict__ v_wg, const float* __restrict__ v_wu,
    ushort* __restrict__ swgT, ushort* __restrict__ swuT,
    ushort* __restrict__ twgT, ushort* __restrict__ twuT,
    ushort* __restrict__ vwgT, ushort* __restrict__ vwuT,
    const float* __restrict__ x, const int* __restrict__ tt,
    const float* __restrict__ t_rw, const float* __restrict__ t_bias,
    const float* __restrict__ v_rw, const float* __restrict__ v_bias,
    int4* __restrict__ ti, float2* __restrict__ tw,
    float* __restrict__ logits_out, ushort* __restrict__ xb) {
  __shared__ uint tile[2][32 * 65];
  int b = blockIdx.x;
  if (b >= PREP_TBLKS) {
    // ---------------- router role ----------------
    int t = (b - PREP_TBLKS) * 4 + (threadIdx.x >> 6);
    int lane = threadIdx.x & 63;
    const float* xr = x + (size_t)t * DIM;
    int vis = tt[t] != 0;
    const float* rw   = vis ? v_rw   : t_rw;
    const float* bias = vis ? v_bias : t_bias;
    float4 xv[4];
#pragma unroll
    for (int i = 0; i < 4; ++i) {
      xv[i] = *(const float4*)(xr + lane * 4 + 256 * i);
      ushort4 o;
      o.x = f2bf(xv[i].x); o.y = f2bf(xv[i].y);
      o.z = f2bf(xv[i].z); o.w = f2bf(xv[i].w);
      *(ushort4*)(xb + (size_t)t * DIM + lane * 4 + 256 * i) = o;
    }
    float lg[8];
#pragma unroll
    for (int e = 0; e < 8; ++e) {
      const float* wrow = rw + (size_t)e * DIM;
      float s = 0.f;
#pragma unroll
      for (int i = 0; i < 4; ++i) {
        float4 wv = *(const float4*)(wrow + lane * 4 + 256 * i);
        s += xv[i].x * wv.x + xv[i].y * wv.y + xv[i].z * wv.z + xv[i].w * wv.w;
      }
#pragma unroll
      for (int off = 32; off > 0; off >>= 1) s += __shfl_xor(s, off);
      lg[e] = s;
    }
    if (lane == 0) {
      float mx = lg[0];
      for (int e = 1; e < 8; ++e) mx = fmaxf(mx, lg[e]);
      float ex[8]; float sum = 0.f;
      for (int e = 0; e < 8; ++e) { ex[e] = __expf(lg[e] - mx); sum += ex[e]; }
      float inv = 1.f / sum;
      float pr[8], sc[8];
      for (int e = 0; e < 8; ++e) { pr[e] = ex[e] * inv; sc[e] = pr[e] + bias[e]; }
      int i0 = 0;
      for (int e = 1; e < 8; ++e) if (sc[e] > sc[i0]) i0 = e;
      int i1 = -1;
      for (int e = 0; e < 8; ++e) {
        if (e == i0) continue;
        if (i1 < 0 || sc[e] > sc[i1]) i1 = e;
      }
      float w0 = pr[i0], w1 = pr[i1];
      float s2 = fmaxf(w0 + w1, 1e-12f);
      w0 /= s2; w1 /= s2;
      ti[t] = make_int4(i0 | (vis << 8), 0, i1, 0);
      tw[t] = make_float2(w0, w1);
      for (int e = 0; e < 8; ++e) logits_out[(size_t)t * 8 + e] = lg[e];
    }
    return;
  }
  // ---------------- wg/wu transpose half-slabs ----------------
  const float* src; ushort* dst; int K = 1024, C, kb, half;
  if (b < 64) {                         // shared wg/wu: 2 x 16 x 2
    int m = b >> 5; int r = b & 31; kb = r >> 1; half = r & 1;
    src = m ? s_wu : s_wg; dst = m ? swuT : swgT; C = 1024;
  } else if (b < 320) {                 // text wg: 8 x 16 x 2
    int i = b - 64; int e = i >> 5; int r = i & 31; kb = r >> 1; half = r & 1;
    src = t_wg + (size_t)e * 524288; dst = twgT + (size_t)e * 524288; C = 512;
  } else if (b < 576) {                 // text wu
    int i = b - 320; int e = i >> 5; int r = i & 31; kb = r >> 1; half = r & 1;
    src = t_wu + (size_t)e * 524288; dst = twuT + (size_t)e * 524288; C = 512;
  } else if (b < 832) {                 // vis wg
    int i = b - 576; int e = i >> 5; int r = i & 31; kb = r >> 1; half = r & 1;
    src = v_wg + (size_t)e * 262144; dst = vwgT + (size_t)e * 262144; C = 256;
  } else {                              // vis wu
    int i = b - 832; int e = i >> 5; int r = i & 31; kb = r >> 1; half = r & 1;
    src = v_wu + (size_t)e * 262144; dst = vwuT + (size_t)e * 262144; C = 256;
  }
  int nbh = C >> 7;                     // half of C/64
  transpose_slab(src, dst, K, C, kb, half * nbh, nbh, tile[0], tile[1]);
}

// ---------------------------------------------------------------------------
// Finalize: ranks via LDS atomics, padded bases, tile->expert maps,
// slot->token lists + slot weights. One block.
// ---------------------------------------------------------------------------
__global__ __launch_bounds__(256) void finalize_kernel(
    int* __restrict__ meta, int4* __restrict__ ti, const float2* __restrict__ tw,
    int* __restrict__ tok_text, int* __restrict__ tok_vis,
    float* __restrict__ sw_text, float* __restrict__ sw_vis) {
  __shared__ int cnt[16];
  __shared__ int sb[16];
  if (threadIdx.x < 16) cnt[threadIdx.x] = 0;
  __syncthreads();
  for (int t = threadIdx.x; t < 1024; t += 256) {
    int4 v = ti[t];
    int e0 = v.x & 0xff, vis = v.x >> 8, e1 = v.z;
    v.y = atomicAdd(&cnt[vis * 8 + e0], 1);
    v.w = atomicAdd(&cnt[vis * 8 + e1], 1);
    ti[t] = v;
  }
  __syncthreads();
  if (threadIdx.x == 0) {
    int bt = 0, tc = 0;
    for (int e = 0; e < 8; ++e) {
      sb[e] = bt; meta[16 + e] = bt;
      int nt = (cnt[e] + 127) >> 7;
      for (int i = 0; i < nt; ++i) meta[40 + tc++] = e;
      bt += nt << 7;
    }
    meta[34] = bt >> 7;
    int bv = 0, vc = 0;
    for (int e = 0; e < 8; ++e) {
      sb[8 + e] = bv; meta[25 + e] = bv;
      int nt = (cnt[8 + e] + 127) >> 7;
      for (int i = 0; i < nt; ++i) meta[72 + vc++] = e;
      bv += nt << 7;
    }
    meta[35] = bv >> 7;
  }
  __syncthreads();
  for (int i = threadIdx.x; i < MAXSLOT; i += 256) {
    tok_text[i] = 0; tok_vis[i] = 0;
    sw_text[i] = 0.f; sw_vis[i] = 0.f;
  }
  __syncthreads();
  for (int t = threadIdx.x; t < 1024; t += 256) {
    int4 v = ti[t];
    float2 wv = tw[t];
    int e0 = v.x & 0xff, vis = v.x >> 8, e1 = v.z;
    int* tl = vis ? tok_vis : tok_text;
    float* wl = vis ? sw_vis : sw_text;
    int s0 = sb[vis * 8 + e0] + v.y, s1 = sb[vis * 8 + e1] + v.w;
    tl[s0] = t; wl[s0] = wv.x;
    tl[s1] = t; wl[s1] = wv.y;
  }
}

// ---------------------------------------------------------------------------
// Up: blocks [0,512): H = silu(Xg@Wg)*(Xg@Wu). BM=128,BN=64,BK=64; dbuf
//     global_load_lds staging with XOR-swizzled sources; swizzled ds_reads.
//     blocks [512,960): wd transpose quarters.
// ---------------------------------------------------------------------------
__global__ __launch_bounds__(256) void up_kernel(
    const ushort* __restrict__ Xb,
    const ushort* __restrict__ swgT, const ushort* __restrict__ swuT,
    const ushort* __restrict__ twgT, const ushort* __restrict__ twuT,
    const ushort* __restrict__ vwgT, const ushort* __restrict__ vwuT,
    const float* __restrict__ s_wd, const float* __restrict__ t_wd,
    const float* __restrict__ v_wd,
    ushort* __restrict__ swdT, ushort* __restrict__ twdT,
    ushort* __restrict__ vwdT,
    const int* __restrict__ meta,
    const int* __restrict__ tok_text, const int* __restrict__ tok_vis,
    ushort* __restrict__ H_sh, ushort* __restrict__ H_tx,
    ushort* __restrict__ H_vs) {
  __shared__ ushort smem[2][16384];    // 64KB: per buf {A:8192, Bg:4096, Bu:4096}
  int b = blockIdx.x;
  int tid = threadIdx.x, lane = tid & 63, w = tid >> 6;

  if (b >= 512) {                      // -------- wd transpose role --------
    int i = b - 512;
    const float* src; ushort* dst; int K, kb, q;
    if (i < 64) {                      // shared wd: 16 kb x 4
      kb = i >> 2; q = i & 3; src = s_wd; dst = swdT; K = 1024;
    } else if (i < 320) {              // text wd: 8e x 8kb x 4
      int j = i - 64; int e = j >> 5; int r = j & 31; kb = r >> 2; q = r & 3;
      src = t_wd + (size_t)e * 524288; dst = twdT + (size_t)e * 524288; K = 512;
    } else {                           // vis wd: 8e x 4kb x 4
      int j = i - 320; int e = j >> 4; int r = j & 15; kb = r >> 2; q = r & 3;
      src = v_wd + (size_t)e * 262144; dst = vwdT + (size_t)e * 262144; K = 256;
    }
    uint* t0 = (uint*)&smem[0][0];
    uint* t1 = t0 + 32 * 65;
    transpose_slab(src, dst, K, 1024, kb, q * 4, 4, t0, t1);
    return;
  }

  int wm = w >> 1, wn = w & 1;
  int fr = lane & 15, fq = lane >> 4;
  int l8 = lane >> 3, l7 = lane & 7;
  int sw = (l7 ^ l8) * 8;              // XOR-swizzled source slot (halfwords)

  const ushort *Bg, *Bu;               // tile base (this block's 64-wide n tile)
  const int* tl = nullptr;
  ushort* Hout; int hstride, t0, ncol0;
  if (b < 128) {                       // shared experts
    int mt = b >> 4, ng = b & 15;
    t0 = mt * 128; ncol0 = ng * 64;
    Bg = swgT + (size_t)ng * 65536; Bu = swuT + (size_t)ng * 65536;
    Hout = H_sh; hstride = 1024;
  } else if (b < 384) {                // text experts
    int rel = b - 128; int mt = rel >> 3, ng = rel & 7;
    if (mt >= meta[34]) return;
    int e = meta[40 + mt];
    t0 = mt * 128; ncol0 = ng * 64;
    Bg = twgT + (size_t)e * 524288 + (size_t)ng * 65536;
    Bu = twuT + (size_t)e * 524288 + (size_t)ng * 65536;
    tl = tok_text; Hout = H_tx; hstride = 512;
  } else {                             // vision experts
    int rel = b - 384; int mt = rel >> 2, ng = rel & 3;
    if (mt >= meta[35]) return;
    int e = meta[72 + mt];
    t0 = mt * 128; ncol0 = ng * 64;
    Bg = vwgT + (size_t)e * 262144 + (size_t)ng * 65536;
    Bu = vwuT + (size_t)e * 262144 + (size_t)ng * 65536;
    tl = tok_vis; Hout = H_vs; hstride = 256;
  }

  const ushort* aptr[4];
#pragma unroll
  for (int i = 0; i < 4; ++i) {
    int row = (w * 4 + i) * 8 + l8;
    int tok = tl ? tl[t0 + row] : (t0 + row);
    aptr[i] = Xb + (size_t)tok * DIM + sw;
  }
  const ushort *bgp[2], *bup[2];
#pragma unroll
  for (int i = 0; i < 2; ++i) {
    int row = (w * 2 + i) * 8 + l8;   // n_local within 64-wide tile
    bgp[i] = Bg + row * 64 + sw;
    bup[i] = Bu + row * 64 + sw;
  }

  auto stage = [&](int buf, int k0, int koffB) {
    ushort* base = smem[buf];
#pragma unroll
    for (int i = 0; i < 4; ++i)
      gld16(aptr[i] + k0, base + (w * 4 + i) * 512);
#pragma unroll
    for (int i = 0; i < 2; ++i) {
      gld16(bgp[i] + koffB, base + 8192 + (w * 2 + i) * 512);
      gld16(bup[i] + koffB, base + 12288 + (w * 2 + i) * 512);
    }
  };

  f32x4 accg[4][2] = {}; f32x4 accu[4][2] = {};
  int sl[2] = { ((0 * 4 + fq) ^ (fr & 7)) * 8, ((1 * 4 + fq) ^ (fr & 7)) * 8 };

  stage(0, 0, 0);
  __syncthreads();
  for (int t = 0; t < 16; ++t) {
    int cur = t & 1;
    if (t < 15) stage(cur ^ 1, (t + 1) * 64, (t + 1) * 4096);
    const ushort* pA = smem[cur];
    const ushort* pBg = smem[cur] + 8192;
    const ushort* pBu = smem[cur] + 12288;
#pragma unroll
    for (int kk = 0; kk < 2; ++kk) {
      bf16x8 a[4], bg[2], bu[2];
#pragma unroll
      for (int m = 0; m < 4; ++m)
        a[m] = *(const bf16x8*)&pA[(wm * 64 + m * 16 + fr) * 64 + sl[kk]];
#pragma unroll
      for (int n = 0; n < 2; ++n) {
        bg[n] = *(const bf16x8*)&pBg[(wn * 32 + n * 16 + fr) * 64 + sl[kk]];
        bu[n] = *(const bf16x8*)&pBu[(wn * 32 + n * 16 + fr) * 64 + sl[kk]];
      }
#pragma unroll
      for (int m = 0; m < 4; ++m)
#pragma unroll
        for (int n = 0; n < 2; ++n) {
          accg[m][n] = __builtin_amdgcn_mfma_f32_16x16x32_bf16(a[m], bg[n], accg[m][n], 0, 0, 0);
          accu[m][n] = __builtin_amdgcn_mfma_f32_16x16x32_bf16(a[m], bu[n], accu[m][n], 0, 0, 0);
        }
    }
    __syncthreads();
  }

#pragma unroll
  for (int m = 0; m < 4; ++m) {
    int rb = t0 + wm * 64 + m * 16 + fq * 4;
#pragma unroll
    for (int n = 0; n < 2; ++n) {
      int col = ncol0 + wn * 32 + n * 16 + fr;
#pragma unroll
      for (int r = 0; r < 4; ++r) {
        float g = accg[m][n][r], u = accu[m][n][r];
        float h = g / (1.f + __expf(-g)) * u;
        Hout[(size_t)(rb + r) * hstride + col] = f2bf(h);
      }
    }
  }
}

// ---------------------------------------------------------------------------
// Down (combine fused): shared -> atomicAdd into zeroed out; routed ->
// atomicAdd(w * acc) at token rows. BM=BN=128, BK=64; dbuf swizzled staging.
// ---------------------------------------------------------------------------
__global__ __launch_bounds__(256) void down_kernel(
    const ushort* __restrict__ H_sh, const ushort* __restrict__ H_tx,
    const ushort* __restrict__ H_vs,
    const ushort* __restrict__ swdT, const ushort* __restrict__ twdT,
    const ushort* __restrict__ vwdT,
    const int* __restrict__ meta,
    const int* __restrict__ tok_text, const int* __restrict__ tok_vis,
    const float* __restrict__ sw_text, const float* __restrict__ sw_vis,
    float* __restrict__ out) {
  __shared__ ushort smem[2][16384];    // 64KB: per buf {A:8192, B:8192}
  int b = blockIdx.x;
  int tid = threadIdx.x, lane = tid & 63, w = tid >> 6;
  int wm = w >> 1, wn = w & 1;
  int fr = lane & 15, fq = lane >> 4;
  int l8 = lane >> 3, l7 = lane & 7;
  int sw = (l7 ^ l8) * 8;

  const ushort *A, *Bt;
  const int* tl = nullptr; const float* wl = nullptr;
  int ksteps, astride, t0, n0;
  if (b < 64) {                        // shared
    int mt = b >> 3, nt = b & 7;
    t0 = mt * 128; n0 = nt * 128;
    A = H_sh; astride = 1024; Bt = swdT; ksteps = 16;
  } else if (b < 320) {                // text
    int rel = b - 64; int mt = rel >> 3, nt = rel & 7;
    if (mt >= meta[34]) return;
    int e = meta[40 + mt];
    t0 = mt * 128; n0 = nt * 128;
    A = H_tx; astride = 512;
    Bt = twdT + (size_t)e * 524288; ksteps = 8;
    tl = tok_text; wl = sw_text;
  } else {                             // vision
    int rel = b - 320; int mt = rel >> 3, nt = rel & 7;
    if (mt >= meta[35]) return;
    int e = meta[72 + mt];
    t0 = mt * 128; n0 = nt * 128;
    A = H_vs; astride = 256;
    Bt = vwdT + (size_t)e * 262144; ksteps = 4;
    tl = tok_vis; wl = sw_vis;
  }

  const ushort *aptr[4], *bptr[4];
#pragma unroll
  for (int i = 0; i < 4; ++i) {
    int c = w * 4 + i;                 // chunk: rows c*8..c*8+7 of 128-row tiles
    int row = c * 8 + l8;
    aptr[i] = A + (size_t)(t0 + row) * astride + sw;
    int nb = (n0 >> 6) + (c >> 3);     // 64-wide n-tile index
    int rowin = row & 63;
    bptr[i] = Bt + (size_t)nb * ksteps * 4096 + rowin * 64 + sw;
  }

  auto stage = [&](int buf, int k0, int koffB) {
    ushort* base = smem[buf];
#pragma unroll
    for (int i = 0; i < 4; ++i) {
      gld16(aptr[i] + k0, base + (w * 4 + i) * 512);
      gld16(bptr[i] + koffB, base + 8192 + (w * 4 + i) * 512);
    }
  };

  f32x4 acc[4][4] = {};
  int sl[2] = { ((0 * 4 + fq) ^ (fr & 7)) * 8, ((1 * 4 + fq) ^ (fr & 7)) * 8 };

  stage(0, 0, 0);
  __syncthreads();
  for (int t = 0; t < ksteps; ++t) {
    int cur = t & 1;
    if (t + 1 < ksteps) stage(cur ^ 1, (t + 1) * 64, (t + 1) * 4096);
    const ushort* pA = smem[cur];
    const ushort* pB = smem[cur] + 8192;
#pragma unroll
    for (int kk = 0; kk < 2; ++kk) {
      bf16x8 a[4], bb[4];
#pragma unroll
      for (int m = 0; m < 4; ++m)
        a[m] = *(const bf16x8*)&pA[(wm * 64 + m * 16 + fr) * 64 + sl[kk]];
#pragma unroll
      for (int n = 0; n < 4; ++n)
        bb[n] = *(const bf16x8*)&pB[(wn * 64 + n * 16 + fr) * 64 + sl[kk]];
#pragma unroll
      for (int m = 0; m < 4; ++m)
#pragma unroll
        for (int n = 0; n < 4; ++n)
          acc[m][n] = __builtin_amdgcn_mfma_f32_16x16x32_bf16(a[m], bb[n], acc[m][n], 0, 0, 0);
    }
    __syncthreads();
  }

  if (!tl) {                           // shared: plain accumulate into out
#pragma unroll
    for (int m = 0; m < 4; ++m)
#pragma unroll
      for (int r = 0; r < 4; ++r) {
        int row = t0 + wm * 64 + m * 16 + fq * 4 + r;
#pragma unroll
        for (int n = 0; n < 4; ++n)
          atomicAdd(&out[(size_t)row * DIM + n0 + wn * 64 + n * 16 + fr],
                    acc[m][n][r]);
      }
  } else {                             // routed: weighted accumulate at token
#pragma unroll
    for (int m = 0; m < 4; ++m)
#pragma unroll
      for (int r = 0; r < 4; ++r) {
        int slot = t0 + wm * 64 + m * 16 + fq * 4 + r;
        float wgt = wl[slot];
        if (wgt == 0.f) continue;
        int tok = tl[slot];
#pragma unroll
        for (int n = 0; n < 4; ++n)
          atomicAdd(&out[(size_t)tok * DIM + n0 + wn * 64 + n * 16 + fr],
                    wgt * acc[m][n][r]);
      }
  }
}

// ---------------------------------------------------------------------------
extern "C" void kernel_launch(void* const* d_in, const int* in_sizes, int n_in,
                              void* d_out, int out_size, void* d_ws, size_t ws_size,
                              hipStream_t stream) {
  const float* x    = (const float*)d_in[0];
  const int*   tt   = (const int*)d_in[1];
  const float* t_rw = (const float*)d_in[2];
  const float* t_b  = (const float*)d_in[3];
  const float* t_wg = (const float*)d_in[4];
  const float* t_wu = (const float*)d_in[5];
  const float* t_wd = (const float*)d_in[6];
  const float* v_rw = (const float*)d_in[7];
  const float* v_b  = (const float*)d_in[8];
  const float* v_wg = (const float*)d_in[9];
  const float* v_wu = (const float*)d_in[10];
  const float* v_wd = (const float*)d_in[11];
  const float* s_wg = (const float*)d_in[12];
  const float* s_wu = (const float*)d_in[13];
  const float* s_wd = (const float*)d_in[14];
  float* out    = (float*)d_out;
  float* logits = out + (size_t)1024 * 1024;

  char* p = (char*)d_ws;
  auto alloc = [&](size_t bytes) {
    char* r = p; p += (bytes + 255) & ~(size_t)255; return r;
  };
  ushort* xb     = (ushort*)alloc((size_t)1024 * 1024 * 2);
  int4*   ti     = (int4*)alloc((size_t)1024 * 16);
  float2* tw     = (float2*)alloc((size_t)1024 * 8);
  int*    meta   = (int*)alloc(512 * 4);
  int*    tok_tx = (int*)alloc(MAXSLOT * 4);
  int*    tok_vs = (int*)alloc(MAXSLOT * 4);
  float*  sw_tx  = (float*)alloc(MAXSLOT * 4);
  float*  sw_vs  = (float*)alloc(MAXSLOT * 4);
  ushort* swdT   = (ushort*)alloc((size_t)1024 * 1024 * 2);
  ushort* twdT   = (ushort*)alloc((size_t)8 * 1024 * 512 * 2);
  ushort* vwdT   = (ushort*)alloc((size_t)8 * 1024 * 256 * 2);
  ushort* H_sh   = (ushort*)alloc((size_t)1024 * 1024 * 2);
  ushort* H_tx   = (ushort*)alloc((size_t)MAXSLOT * 512 * 2);
  ushort* H_vs   = (ushort*)alloc((size_t)MAXSLOT * 256 * 2);
  ushort* swgT   = (ushort*)alloc((size_t)1024 * 1024 * 2);
  ushort* swuT   = (ushort*)alloc((size_t)1024 * 1024 * 2);
  ushort* twgT   = (ushort*)alloc((size_t)8 * 512 * 1024 * 2);
  ushort* twuT   = (ushort*)alloc((size_t)8 * 512 * 1024 * 2);
  ushort* vwgT   = (ushort*)alloc((size_t)8 * 256 * 1024 * 2);
  ushort* vwuT   = (ushort*)alloc((size_t)8 * 256 * 1024 * 2);

  // zero the out region (logits region untouched); down accumulates into it
  hipMemsetAsync(out, 0, (size_t)1024 * 1024 * 4, stream);

  prep_router_kernel<<<PREP_TBLKS + 256, 256, 0, stream>>>(
      s_wg, s_wu, t_wg, t_wu, v_wg, v_wu,
      swgT, swuT, twgT, twuT, vwgT, vwuT,
      x, tt, t_rw, t_b, v_rw, v_b, ti, tw, logits, xb);
  finalize_kernel<<<1, 256, 0, stream>>>(meta, ti, tw, tok_tx, tok_vs,
                                         sw_tx, sw_vs);
  up_kernel<<<960, 256, 0, stream>>>(xb, swgT, swuT, twgT, twuT, vwgT, vwuT,
                                     s_wd, t_wd, v_wd, swdT, twdT, vwdT,
                                     meta, tok_tx, tok_vs, H_sh, H_tx, H_vs);
  down_kernel<<<576, 256, 0, stream>>>(H_sh, H_tx, H_vs, swdT, twdT, vwdT,
                                       meta, tok_tx, tok_vs, sw_tx, sw_vs, out);
}

// Round 13
// 77.116 us; speedup vs baseline: 1.0394x; 1.0394x over previous
//
#include <hip/hip_runtime.h>

typedef short bf16x8 __attribute__((ext_vector_type(8)));
typedef float f32x4 __attribute__((ext_vector_type(4)));
typedef ushort ushort8 __attribute__((ext_vector_type(8)));

#define DIM 1024
#define MAXSLOT 4096
#define PREP_TBLKS 1088   // transpose blocks in prep kernel (wg/wu, split x2)
#define UP_TBLKS 448      // wd transpose blocks at the FRONT of up's grid

__device__ __forceinline__ ushort f2bf(float f) {
  unsigned u = __float_as_uint(f);
  u += 0x7fffu + ((u >> 16) & 1u);   // round-to-nearest-even
  return (ushort)(u >> 16);
}

__device__ __forceinline__ void gld16(const ushort* g, ushort* l) {
  __builtin_amdgcn_global_load_lds(
      (const __attribute__((address_space(1))) unsigned int*)g,
      (__attribute__((address_space(3))) unsigned int*)l, 16, 0, 0);
}

// ---------------------------------------------------------------------------
// Transpose a sub-range of one 64-row slab of fp32 [K][C] into tiled bf16
// T[C/64][K/64][64][64] (tile [n_local][k_local], 8KB contiguous per tile).
// bf16-PAIR-PACKED LDS tile (8.3KB/buf, dbuf -> full wave occupancy).
// ---------------------------------------------------------------------------
__device__ __forceinline__ void transpose_slab(
    const float* __restrict__ src, ushort* __restrict__ dst,
    int K, int C, int kb, int nb0, int nbcnt, uint* tile0, uint* tile1) {
  int k0 = kb << 6;
  int tid = threadIdx.x;
  int tx = tid & 15, ty = tid >> 4;   // load: cols 4tx.., pair-rows {ty, 16+ty}
  int sx = tid & 7,  sy = tid >> 3;   // store: out rows {sy, 32+sy}, ks 8sx..
  int kt = K >> 6;
  uint* bufs[2] = {tile0, tile1};
  float4 v[4];                        // [p*2+q]: row 2*(p*16+ty)+q

  auto loadT = [&](int nb) {
#pragma unroll
    for (int p = 0; p < 2; ++p)
#pragma unroll
      for (int q = 0; q < 2; ++q)
        v[p * 2 + q] = *(const float4*)(
            src + (size_t)(k0 + (p * 16 + ty) * 2 + q) * C + (nb << 6) + tx * 4);
  };
  auto packW = [&](uint* buf) {
#pragma unroll
    for (int p = 0; p < 2; ++p) {
      uint u[4];
#pragma unroll
      for (int c = 0; c < 4; ++c) {
        float lo = ((const float*)&v[p * 2])[c];
        float hi = ((const float*)&v[p * 2 + 1])[c];
        u[c] = (uint)f2bf(lo) | ((uint)f2bf(hi) << 16);
      }
      *(uint4*)&buf[(p * 16 + ty) * 65 + tx * 4] = *(uint4*)u;
    }
  };

  loadT(nb0); packW(bufs[0]);
  __syncthreads();
  for (int i = 0; i < nbcnt; ++i) {
    bool more = i + 1 < nbcnt;
    if (more) loadT(nb0 + i + 1);
    uint* cur = bufs[i & 1];
    ushort* tb = dst + ((size_t)(nb0 + i) * kt + kb) * 4096;
#pragma unroll
    for (int p = 0; p < 2; ++p) {
      int n = p * 32 + sy;
      ushort8 o;
#pragma unroll
      for (int jj = 0; jj < 4; ++jj) {
        uint u = cur[(4 * sx + jj) * 65 + n];
        o[2 * jj]     = (ushort)(u & 0xffff);
        o[2 * jj + 1] = (ushort)(u >> 16);
      }
      *(ushort8*)(tb + n * 64 + sx * 8) = o;
    }
    if (more) packW(bufs[(i + 1) & 1]);
    __syncthreads();
  }
}

// meta layout (ints): [16..23] base_text; [25..32] base_vis; [34] ntiles_text;
// [35] ntiles_vis; [40..71] tile_expert_text; [72..103] tile_expert_vis.

// ---------------------------------------------------------------------------
// Fused: blocks [0,1088): wg/wu transpose half-slabs. blocks [1088,1344): router.
// ---------------------------------------------------------------------------
__global__ __launch_bounds__(256) void prep_router_kernel(
    const float* __restrict__ s_wg, const float* __restrict__ s_wu,
    const float* __restrict__ t_wg, const float* __restrict__ t_wu,
    const float* __restrict__ v_wg, const float* __restrict__ v_wu,
    ushort* __restrict__ swgT, ushort* __restrict__ swuT,
    ushort* __restrict__ twgT, ushort* __restrict__ twuT,
    ushort* __restrict__ vwgT, ushort* __restrict__ vwuT,
    const float* __restrict__ x, const int* __restrict__ tt,
    const float* __restrict__ t_rw, const float* __restrict__ t_bias,
    const float* __restrict__ v_rw, const float* __restrict__ v_bias,
    int4* __restrict__ ti, float2* __restrict__ tw,
    float* __restrict__ logits_out, ushort* __restrict__ xb) {
  __shared__ uint tile[2][32 * 65];
  int b = blockIdx.x;
  if (b >= PREP_TBLKS) {
    // ---------------- router role ----------------
    int t = (b - PREP_TBLKS) * 4 + (threadIdx.x >> 6);
    int lane = threadIdx.x & 63;
    const float* xr = x + (size_t)t * DIM;
    int vis = tt[t] != 0;
    const float* rw   = vis ? v_rw   : t_rw;
    const float* bias = vis ? v_bias : t_bias;
    float4 xv[4];
#pragma unroll
    for (int i = 0; i < 4; ++i) {
      xv[i] = *(const float4*)(xr + lane * 4 + 256 * i);
      ushort4 o;
      o.x = f2bf(xv[i].x); o.y = f2bf(xv[i].y);
      o.z = f2bf(xv[i].z); o.w = f2bf(xv[i].w);
      *(ushort4*)(xb + (size_t)t * DIM + lane * 4 + 256 * i) = o;
    }
    float lg[8];
#pragma unroll
    for (int e = 0; e < 8; ++e) {
      const float* wrow = rw + (size_t)e * DIM;
      float s = 0.f;
#pragma unroll
      for (int i = 0; i < 4; ++i) {
        float4 wv = *(const float4*)(wrow + lane * 4 + 256 * i);
        s += xv[i].x * wv.x + xv[i].y * wv.y + xv[i].z * wv.z + xv[i].w * wv.w;
      }
#pragma unroll
      for (int off = 32; off > 0; off >>= 1) s += __shfl_xor(s, off);
      lg[e] = s;
    }
    if (lane == 0) {
      float mx = lg[0];
      for (int e = 1; e < 8; ++e) mx = fmaxf(mx, lg[e]);
      float ex[8]; float sum = 0.f;
      for (int e = 0; e < 8; ++e) { ex[e] = __expf(lg[e] - mx); sum += ex[e]; }
      float inv = 1.f / sum;
      float pr[8], sc[8];
      for (int e = 0; e < 8; ++e) { pr[e] = ex[e] * inv; sc[e] = pr[e] + bias[e]; }
      int i0 = 0;
      for (int e = 1; e < 8; ++e) if (sc[e] > sc[i0]) i0 = e;
      int i1 = -1;
      for (int e = 0; e < 8; ++e) {
        if (e == i0) continue;
        if (i1 < 0 || sc[e] > sc[i1]) i1 = e;
      }
      float w0 = pr[i0], w1 = pr[i1];
      float s2 = fmaxf(w0 + w1, 1e-12f);
      w0 /= s2; w1 /= s2;
      ti[t] = make_int4(i0 | (vis << 8), 0, i1, 0);
      tw[t] = make_float2(w0, w1);
      for (int e = 0; e < 8; ++e) logits_out[(size_t)t * 8 + e] = lg[e];
    }
    return;
  }
  // ---------------- wg/wu transpose half-slabs ----------------
  const float* src; ushort* dst; int K = 1024, C, kb, half;
  if (b < 64) {                         // shared wg/wu: 2 x 16 x 2
    int m = b >> 5; int r = b & 31; kb = r >> 1; half = r & 1;
    src = m ? s_wu : s_wg; dst = m ? swuT : swgT; C = 1024;
  } else if (b < 320) {                 // text wg: 8 x 16 x 2
    int i = b - 64; int e = i >> 5; int r = i & 31; kb = r >> 1; half = r & 1;
    src = t_wg + (size_t)e * 524288; dst = twgT + (size_t)e * 524288; C = 512;
  } else if (b < 576) {                 // text wu
    int i = b - 320; int e = i >> 5; int r = i & 31; kb = r >> 1; half = r & 1;
    src = t_wu + (size_t)e * 524288; dst = twuT + (size_t)e * 524288; C = 512;
  } else if (b < 832) {                 // vis wg
    int i = b - 576; int e = i >> 5; int r = i & 31; kb = r >> 1; half = r & 1;
    src = v_wg + (size_t)e * 262144; dst = vwgT + (size_t)e * 262144; C = 256;
  } else {                              // vis wu
    int i = b - 832; int e = i >> 5; int r = i & 31; kb = r >> 1; half = r & 1;
    src = v_wu + (size_t)e * 262144; dst = vwuT + (size_t)e * 262144; C = 256;
  }
  int nbh = C >> 7;                     // half of C/64
  transpose_slab(src, dst, K, C, kb, half * nbh, nbh, tile[0], tile[1]);
}

// ---------------------------------------------------------------------------
// Finalize: ranks via LDS atomics, padded bases, tile->expert maps,
// slot->token lists. One block.
// ---------------------------------------------------------------------------
__global__ __launch_bounds__(256) void finalize_kernel(
    int* __restrict__ meta, int4* __restrict__ ti,
    int* __restrict__ tok_text, int* __restrict__ tok_vis) {
  __shared__ int cnt[16];
  __shared__ int sb[16];
  if (threadIdx.x < 16) cnt[threadIdx.x] = 0;
  __syncthreads();
  for (int t = threadIdx.x; t < 1024; t += 256) {
    int4 v = ti[t];
    int e0 = v.x & 0xff, vis = v.x >> 8, e1 = v.z;
    v.y = atomicAdd(&cnt[vis * 8 + e0], 1);
    v.w = atomicAdd(&cnt[vis * 8 + e1], 1);
    ti[t] = v;
  }
  __syncthreads();
  if (threadIdx.x == 0) {
    int bt = 0, tc = 0;
    for (int e = 0; e < 8; ++e) {
      sb[e] = bt; meta[16 + e] = bt;
      int nt = (cnt[e] + 127) >> 7;
      for (int i = 0; i < nt; ++i) meta[40 + tc++] = e;
      bt += nt << 7;
    }
    meta[34] = bt >> 7;
    int bv = 0, vc = 0;
    for (int e = 0; e < 8; ++e) {
      sb[8 + e] = bv; meta[25 + e] = bv;
      int nt = (cnt[8 + e] + 127) >> 7;
      for (int i = 0; i < nt; ++i) meta[72 + vc++] = e;
      bv += nt << 7;
    }
    meta[35] = bv >> 7;
  }
  __syncthreads();
  for (int i = threadIdx.x; i < MAXSLOT; i += 256) { tok_text[i] = 0; tok_vis[i] = 0; }
  __syncthreads();
  for (int t = threadIdx.x; t < 1024; t += 256) {
    int4 v = ti[t];
    int e0 = v.x & 0xff, vis = v.x >> 8, e1 = v.z;
    int* tl = vis ? tok_vis : tok_text;
    tl[sb[vis * 8 + e0] + v.y] = t;
    tl[sb[vis * 8 + e1] + v.w] = t;
  }
}

// ---------------------------------------------------------------------------
// Up: blocks [0,448): wd transpose quarters (FIRST: BW-bound blocks interleave
//     with compute-bound GEMM blocks instead of forming a serialized tail).
//     blocks [448,960): H = silu(Xg@Wg)*(Xg@Wu). BM=128,BN=64,BK=64; dbuf
//     global_load_lds staging with XOR-swizzled sources; swizzled ds_reads.
// ---------------------------------------------------------------------------
__global__ __launch_bounds__(256) void up_kernel(
    const ushort* __restrict__ Xb,
    const ushort* __restrict__ swgT, const ushort* __restrict__ swuT,
    const ushort* __restrict__ twgT, const ushort* __restrict__ twuT,
    const ushort* __restrict__ vwgT, const ushort* __restrict__ vwuT,
    const float* __restrict__ s_wd, const float* __restrict__ t_wd,
    const float* __restrict__ v_wd,
    ushort* __restrict__ swdT, ushort* __restrict__ twdT,
    ushort* __restrict__ vwdT,
    const int* __restrict__ meta,
    const int* __restrict__ tok_text, const int* __restrict__ tok_vis,
    ushort* __restrict__ H_sh, ushort* __restrict__ H_tx,
    ushort* __restrict__ H_vs) {
  __shared__ ushort smem[2][16384];    // 64KB: per buf {A:8192, Bg:4096, Bu:4096}
  int b = blockIdx.x;
  int tid = threadIdx.x, lane = tid & 63, w = tid >> 6;

  if (b < UP_TBLKS) {                  // -------- wd transpose role --------
    int i = b;
    const float* src; ushort* dst; int K, kb, q;
    if (i < 64) {                      // shared wd: 16 kb x 4
      kb = i >> 2; q = i & 3; src = s_wd; dst = swdT; K = 1024;
    } else if (i < 320) {              // text wd: 8e x 8kb x 4
      int j = i - 64; int e = j >> 5; int r = j & 31; kb = r >> 2; q = r & 3;
      src = t_wd + (size_t)e * 524288; dst = twdT + (size_t)e * 524288; K = 512;
    } else {                           // vis wd: 8e x 4kb x 4
      int j = i - 320; int e = j >> 4; int r = j & 15; kb = r >> 2; q = r & 3;
      src = v_wd + (size_t)e * 262144; dst = vwdT + (size_t)e * 262144; K = 256;
    }
    uint* t0 = (uint*)&smem[0][0];
    uint* t1 = t0 + 32 * 65;
    transpose_slab(src, dst, K, 1024, kb, q * 4, 4, t0, t1);
    return;
  }
  b -= UP_TBLKS;                       // GEMM role: b in [0,512)

  int wm = w >> 1, wn = w & 1;
  int fr = lane & 15, fq = lane >> 4;
  int l8 = lane >> 3, l7 = lane & 7;
  int sw = (l7 ^ l8) * 8;              // XOR-swizzled source slot (halfwords)

  const ushort *Bg, *Bu;               // tile base (this block's 64-wide n tile)
  const int* tl = nullptr;
  ushort* Hout; int hstride, t0, ncol0;
  if (b < 128) {                       // shared experts
    int mt = b >> 4, ng = b & 15;
    t0 = mt * 128; ncol0 = ng * 64;
    Bg = swgT + (size_t)ng * 65536; Bu = swuT + (size_t)ng * 65536;
    Hout = H_sh; hstride = 1024;
  } else if (b < 384) {                // text experts
    int rel = b - 128; int mt = rel >> 3, ng = rel & 7;
    if (mt >= meta[34]) return;
    int e = meta[40 + mt];
    t0 = mt * 128; ncol0 = ng * 64;
    Bg = twgT + (size_t)e * 524288 + (size_t)ng * 65536;
    Bu = twuT + (size_t)e * 524288 + (size_t)ng * 65536;
    tl = tok_text; Hout = H_tx; hstride = 512;
  } else {                             // vision experts
    int rel = b - 384; int mt = rel >> 2, ng = rel & 3;
    if (mt >= meta[35]) return;
    int e = meta[72 + mt];
    t0 = mt * 128; ncol0 = ng * 64;
    Bg = vwgT + (size_t)e * 262144 + (size_t)ng * 65536;
    Bu = vwuT + (size_t)e * 262144 + (size_t)ng * 65536;
    tl = tok_vis; Hout = H_vs; hstride = 256;
  }

  const ushort* aptr[4];
#pragma unroll
  for (int i = 0; i < 4; ++i) {
    int row = (w * 4 + i) * 8 + l8;
    int tok = tl ? tl[t0 + row] : (t0 + row);
    aptr[i] = Xb + (size_t)tok * DIM + sw;
  }
  const ushort *bgp[2], *bup[2];
#pragma unroll
  for (int i = 0; i < 2; ++i) {
    int row = (w * 2 + i) * 8 + l8;   // n_local within 64-wide tile
    bgp[i] = Bg + row * 64 + sw;
    bup[i] = Bu + row * 64 + sw;
  }

  auto stage = [&](int buf, int k0, int koffB) {
    ushort* base = smem[buf];
#pragma unroll
    for (int i = 0; i < 4; ++i)
      gld16(aptr[i] + k0, base + (w * 4 + i) * 512);
#pragma unroll
    for (int i = 0; i < 2; ++i) {
      gld16(bgp[i] + koffB, base + 8192 + (w * 2 + i) * 512);
      gld16(bup[i] + koffB, base + 12288 + (w * 2 + i) * 512);
    }
  };

  f32x4 accg[4][2] = {}; f32x4 accu[4][2] = {};
  int sl[2] = { ((0 * 4 + fq) ^ (fr & 7)) * 8, ((1 * 4 + fq) ^ (fr & 7)) * 8 };

  stage(0, 0, 0);
  __syncthreads();
  for (int t = 0; t < 16; ++t) {
    int cur = t & 1;
    if (t < 15) stage(cur ^ 1, (t + 1) * 64, (t + 1) * 4096);
    const ushort* pA = smem[cur];
    const ushort* pBg = smem[cur] + 8192;
    const ushort* pBu = smem[cur] + 12288;
#pragma unroll
    for (int kk = 0; kk < 2; ++kk) {
      bf16x8 a[4], bg[2], bu[2];
#pragma unroll
      for (int m = 0; m < 4; ++m)
        a[m] = *(const bf16x8*)&pA[(wm * 64 + m * 16 + fr) * 64 + sl[kk]];
#pragma unroll
      for (int n = 0; n < 2; ++n) {
        bg[n] = *(const bf16x8*)&pBg[(wn * 32 + n * 16 + fr) * 64 + sl[kk]];
        bu[n] = *(const bf16x8*)&pBu[(wn * 32 + n * 16 + fr) * 64 + sl[kk]];
      }
#pragma unroll
      for (int m = 0; m < 4; ++m)
#pragma unroll
        for (int n = 0; n < 2; ++n) {
          accg[m][n] = __builtin_amdgcn_mfma_f32_16x16x32_bf16(a[m], bg[n], accg[m][n], 0, 0, 0);
          accu[m][n] = __builtin_amdgcn_mfma_f32_16x16x32_bf16(a[m], bu[n], accu[m][n], 0, 0, 0);
        }
    }
    __syncthreads();
  }

#pragma unroll
  for (int m = 0; m < 4; ++m) {
    int rb = t0 + wm * 64 + m * 16 + fq * 4;
#pragma unroll
    for (int n = 0; n < 2; ++n) {
      int col = ncol0 + wn * 32 + n * 16 + fr;
#pragma unroll
      for (int r = 0; r < 4; ++r) {
        float g = accg[m][n][r], u = accu[m][n][r];
        float h = g / (1.f + __expf(-g)) * u;
        Hout[(size_t)(rb + r) * hstride + col] = f2bf(h);
      }
    }
  }
}

// ---------------------------------------------------------------------------
// Down: shared -> out directly; routed -> pd[slot][1024]. BM=BN=128, BK=64;
// dbuf staging with XOR-swizzled sources + swizzled ds_reads.
// ---------------------------------------------------------------------------
__global__ __launch_bounds__(256) void down_kernel(
    const ushort* __restrict__ H_sh, const ushort* __restrict__ H_tx,
    const ushort* __restrict__ H_vs,
    const ushort* __restrict__ swdT, const ushort* __restrict__ twdT,
    const ushort* __restrict__ vwdT,
    const int* __restrict__ meta, float* __restrict__ out,
    float* __restrict__ pd_tx, float* __restrict__ pd_vs) {
  __shared__ ushort smem[2][16384];    // 64KB: per buf {A:8192, B:8192}
  int b = blockIdx.x;
  int tid = threadIdx.x, lane = tid & 63, w = tid >> 6;
  int wm = w >> 1, wn = w & 1;
  int fr = lane & 15, fq = lane >> 4;
  int l8 = lane >> 3, l7 = lane & 7;
  int sw = (l7 ^ l8) * 8;

  const ushort *A, *Bt; float* O;
  int ksteps, astride, t0, n0;
  if (b < 64) {                        // shared
    int mt = b >> 3, nt = b & 7;
    t0 = mt * 128; n0 = nt * 128;
    A = H_sh; astride = 1024; Bt = swdT; ksteps = 16;
    O = out;
  } else if (b < 320) {                // text
    int rel = b - 64; int mt = rel >> 3, nt = rel & 7;
    if (mt >= meta[34]) return;
    int e = meta[40 + mt];
    t0 = mt * 128; n0 = nt * 128;
    A = H_tx; astride = 512;
    Bt = twdT + (size_t)e * 524288; ksteps = 8;
    O = pd_tx;
  } else {                             // vision
    int rel = b - 320; int mt = rel >> 3, nt = rel & 7;
    if (mt >= meta[35]) return;
    int e = meta[72 + mt];
    t0 = mt * 128; n0 = nt * 128;
    A = H_vs; astride = 256;
    Bt = vwdT + (size_t)e * 262144; ksteps = 4;
    O = pd_vs;
  }

  const ushort *aptr[4], *bptr[4];
#pragma unroll
  for (int i = 0; i < 4; ++i) {
    int c = w * 4 + i;                 // chunk: rows c*8..c*8+7 of 128-row tiles
    int row = c * 8 + l8;
    aptr[i] = A + (size_t)(t0 + row) * astride + sw;
    int nb = (n0 >> 6) + (c >> 3);     // 64-wide n-tile index
    int rowin = row & 63;
    bptr[i] = Bt + (size_t)nb * ksteps * 4096 + rowin * 64 + sw;
  }

  auto stage = [&](int buf, int k0, int koffB) {
    ushort* base = smem[buf];
#pragma unroll
    for (int i = 0; i < 4; ++i) {
      gld16(aptr[i] + k0, base + (w * 4 + i) * 512);
      gld16(bptr[i] + koffB, base + 8192 + (w * 4 + i) * 512);
    }
  };

  f32x4 acc[4][4] = {};
  int sl[2] = { ((0 * 4 + fq) ^ (fr & 7)) * 8, ((1 * 4 + fq) ^ (fr & 7)) * 8 };

  stage(0, 0, 0);
  __syncthreads();
  for (int t = 0; t < ksteps; ++t) {
    int cur = t & 1;
    if (t + 1 < ksteps) stage(cur ^ 1, (t + 1) * 64, (t + 1) * 4096);
    const ushort* pA = smem[cur];
    const ushort* pB = smem[cur] + 8192;
#pragma unroll
    for (int kk = 0; kk < 2; ++kk) {
      bf16x8 a[4], bb[4];
#pragma unroll
      for (int m = 0; m < 4; ++m)
        a[m] = *(const bf16x8*)&pA[(wm * 64 + m * 16 + fr) * 64 + sl[kk]];
#pragma unroll
      for (int n = 0; n < 4; ++n)
        bb[n] = *(const bf16x8*)&pB[(wn * 64 + n * 16 + fr) * 64 + sl[kk]];
#pragma unroll
      for (int m = 0; m < 4; ++m)
#pragma unroll
        for (int n = 0; n < 4; ++n)
          acc[m][n] = __builtin_amdgcn_mfma_f32_16x16x32_bf16(a[m], bb[n], acc[m][n], 0, 0, 0);
    }
    __syncthreads();
  }

#pragma unroll
  for (int m = 0; m < 4; ++m)
#pragma unroll
    for (int n = 0; n < 4; ++n)
#pragma unroll
      for (int r = 0; r < 4; ++r)
        O[(size_t)(t0 + wm * 64 + m * 16 + fq * 4 + r) * DIM
          + n0 + wn * 64 + n * 16 + fr] = acc[m][n][r];
}

// ---------------------------------------------------------------------------
// Combine: out[t] += w0 * pd[slot0] + w1 * pd[slot1]
// ---------------------------------------------------------------------------
__global__ __launch_bounds__(256) void combine_kernel(
    const int4* __restrict__ ti, const float2* __restrict__ tw,
    const int* __restrict__ meta,
    const float* __restrict__ pd_tx, const float* __restrict__ pd_vs,
    float* __restrict__ out) {
  int t = blockIdx.x;
  int4 v = ti[t]; float2 wv = tw[t];
  int e0 = v.x & 0xff, vis = v.x >> 8, e1 = v.z;
  const int* base = meta + (vis ? 25 : 16);
  const float* pd = vis ? pd_vs : pd_tx;
  size_t s0 = base[e0] + v.y, s1 = base[e1] + v.w;
  int d = threadIdx.x * 4;
  f32x4 a  = *(const f32x4*)(out + (size_t)t * DIM + d);
  f32x4 p0 = *(const f32x4*)(pd + s0 * DIM + d);
  f32x4 p1 = *(const f32x4*)(pd + s1 * DIM + d);
#pragma unroll
  for (int j = 0; j < 4; ++j) a[j] = a[j] + wv.x * p0[j] + wv.y * p1[j];
  *(f32x4*)(out + (size_t)t * DIM + d) = a;
}

// ---------------------------------------------------------------------------
extern "C" void kernel_launch(void* const* d_in, const int* in_sizes, int n_in,
                              void* d_out, int out_size, void* d_ws, size_t ws_size,
                              hipStream_t stream) {
  const float* x    = (const float*)d_in[0];
  const int*   tt   = (const int*)d_in[1];
  const float* t_rw = (const float*)d_in[2];
  const float* t_b  = (const float*)d_in[3];
  const float* t_wg = (const float*)d_in[4];
  const float* t_wu = (const float*)d_in[5];
  const float* t_wd = (const float*)d_in[6];
  const float* v_rw = (const float*)d_in[7];
  const float* v_b  = (const float*)d_in[8];
  const float* v_wg = (const float*)d_in[9];
  const float* v_wu = (const float*)d_in[10];
  const float* v_wd = (const float*)d_in[11];
  const float* s_wg = (const float*)d_in[12];
  const float* s_wu = (const float*)d_in[13];
  const float* s_wd = (const float*)d_in[14];
  float* out    = (float*)d_out;
  float* logits = out + (size_t)1024 * 1024;

  char* p = (char*)d_ws;
  auto alloc = [&](size_t bytes) {
    char* r = p; p += (bytes + 255) & ~(size_t)255; return r;
  };
  ushort* xb     = (ushort*)alloc((size_t)1024 * 1024 * 2);
  int4*   ti     = (int4*)alloc((size_t)1024 * 16);
  float2* tw     = (float2*)alloc((size_t)1024 * 8);
  int*    meta   = (int*)alloc(512 * 4);
  int*    tok_tx = (int*)alloc(MAXSLOT * 4);
  int*    tok_vs = (int*)alloc(MAXSLOT * 4);
  ushort* swdT   = (ushort*)alloc((size_t)1024 * 1024 * 2);
  ushort* twdT   = (ushort*)alloc((size_t)8 * 1024 * 512 * 2);
  ushort* vwdT   = (ushort*)alloc((size_t)8 * 1024 * 256 * 2);
  ushort* H_sh   = (ushort*)alloc((size_t)1024 * 1024 * 2);
  ushort* H_tx   = (ushort*)alloc((size_t)MAXSLOT * 512 * 2);
  ushort* H_vs   = (ushort*)alloc((size_t)MAXSLOT * 256 * 2);
  // union region: up-only weights (28MB) overlaid later by pd buffers (32MB)
  char* upmark = p;
  ushort* swgT   = (ushort*)alloc((size_t)1024 * 1024 * 2);
  ushort* swuT   = (ushort*)alloc((size_t)1024 * 1024 * 2);
  ushort* twgT   = (ushort*)alloc((size_t)8 * 512 * 1024 * 2);
  ushort* twuT   = (ushort*)alloc((size_t)8 * 512 * 1024 * 2);
  ushort* vwgT   = (ushort*)alloc((size_t)8 * 256 * 1024 * 2);
  ushort* vwuT   = (ushort*)alloc((size_t)8 * 256 * 1024 * 2);
  float* pd_tx = (float*)upmark;                       // 16 MB
  float* pd_vs = (float*)(upmark + (size_t)MAXSLOT * DIM * 4);  // 16 MB

  prep_router_kernel<<<PREP_TBLKS + 256, 256, 0, stream>>>(
      s_wg, s_wu, t_wg, t_wu, v_wg, v_wu,
      swgT, swuT, twgT, twuT, vwgT, vwuT,
      x, tt, t_rw, t_b, v_rw, v_b, ti, tw, logits, xb);
  finalize_kernel<<<1, 256, 0, stream>>>(meta, ti, tok_tx, tok_vs);
  up_kernel<<<960, 256, 0, stream>>>(xb, swgT, swuT, twgT, twuT, vwgT, vwuT,
                                     s_wd, t_wd, v_wd, swdT, twdT, vwdT,
                                     meta, tok_tx, tok_vs, H_sh, H_tx, H_vs);
  down_kernel<<<576, 256, 0, stream>>>(H_sh, H_tx, H_vs, swdT, twdT, vwdT,
                                       meta, out, pd_tx, pd_vs);
  combine_kernel<<<1024, 256, 0, stream>>>(ti, tw, meta, pd_tx, pd_vs, out);
}

// Round 14
// 72.406 us; speedup vs baseline: 1.1070x; 1.0651x over previous
//
#include <hip/hip_runtime.h>

typedef short bf16x8 __attribute__((ext_vector_type(8)));
typedef float f32x4 __attribute__((ext_vector_type(4)));
typedef ushort ushort8 __attribute__((ext_vector_type(8)));

#define DIM 1024
#define MAXSLOT 4096
#define PREP_TBLKS 2176   // transpose blocks in prep kernel (wg/wu, split x4)

__device__ __forceinline__ ushort f2bf(float f) {
  unsigned u = __float_as_uint(f);
  u += 0x7fffu + ((u >> 16) & 1u);   // round-to-nearest-even
  return (ushort)(u >> 16);
}

__device__ __forceinline__ void gld16(const ushort* g, ushort* l) {
  __builtin_amdgcn_global_load_lds(
      (const __attribute__((address_space(1))) unsigned int*)g,
      (__attribute__((address_space(3))) unsigned int*)l, 16, 0, 0);
}

// ---------------------------------------------------------------------------
// Transpose a sub-range of one 64-row slab of fp32 [K][C] into tiled bf16
// T[C/64][K/64][64][64] (tile [n_local][k_local], 8KB contiguous per tile).
// bf16-PAIR-PACKED LDS tile (8.3KB/buf, dbuf -> full wave occupancy).
// ---------------------------------------------------------------------------
__device__ __forceinline__ void transpose_slab(
    const float* __restrict__ src, ushort* __restrict__ dst,
    int K, int C, int kb, int nb0, int nbcnt, uint* tile0, uint* tile1) {
  int k0 = kb << 6;
  int tid = threadIdx.x;
  int tx = tid & 15, ty = tid >> 4;   // load: cols 4tx.., pair-rows {ty, 16+ty}
  int sx = tid & 7,  sy = tid >> 3;   // store: out rows {sy, 32+sy}, ks 8sx..
  int kt = K >> 6;
  uint* bufs[2] = {tile0, tile1};
  float4 v[4];                        // [p*2+q]: row 2*(p*16+ty)+q

  auto loadT = [&](int nb) {
#pragma unroll
    for (int p = 0; p < 2; ++p)
#pragma unroll
      for (int q = 0; q < 2; ++q)
        v[p * 2 + q] = *(const float4*)(
            src + (size_t)(k0 + (p * 16 + ty) * 2 + q) * C + (nb << 6) + tx * 4);
  };
  auto packW = [&](uint* buf) {
#pragma unroll
    for (int p = 0; p < 2; ++p) {
      uint u[4];
#pragma unroll
      for (int c = 0; c < 4; ++c) {
        float lo = ((const float*)&v[p * 2])[c];
        float hi = ((const float*)&v[p * 2 + 1])[c];
        u[c] = (uint)f2bf(lo) | ((uint)f2bf(hi) << 16);
      }
      *(uint4*)&buf[(p * 16 + ty) * 65 + tx * 4] = *(uint4*)u;
    }
  };

  loadT(nb0); packW(bufs[0]);
  __syncthreads();
  for (int i = 0; i < nbcnt; ++i) {
    bool more = i + 1 < nbcnt;
    if (more) loadT(nb0 + i + 1);
    uint* cur = bufs[i & 1];
    ushort* tb = dst + ((size_t)(nb0 + i) * kt + kb) * 4096;
#pragma unroll
    for (int p = 0; p < 2; ++p) {
      int n = p * 32 + sy;
      ushort8 o;
#pragma unroll
      for (int jj = 0; jj < 4; ++jj) {
        uint u = cur[(4 * sx + jj) * 65 + n];
        o[2 * jj]     = (ushort)(u & 0xffff);
        o[2 * jj + 1] = (ushort)(u >> 16);
      }
      *(ushort8*)(tb + n * 64 + sx * 8) = o;
    }
    if (more) packW(bufs[(i + 1) & 1]);
    __syncthreads();
  }
}

// meta layout (ints): [16..23] base_text; [25..32] base_vis; [34] ntiles_text;
// [35] ntiles_vis; [40..71] tile_expert_text; [72..103] tile_expert_vis.

// ---------------------------------------------------------------------------
// Fused: blocks [0,2176): wg/wu transpose quarter-slabs.
//        blocks [2176,2432): router.
// ---------------------------------------------------------------------------
__global__ __launch_bounds__(256) void prep_router_kernel(
    const float* __restrict__ s_wg, const float* __restrict__ s_wu,
    const float* __restrict__ t_wg, const float* __restrict__ t_wu,
    const float* __restrict__ v_wg, const float* __restrict__ v_wu,
    ushort* __restrict__ swgT, ushort* __restrict__ swuT,
    ushort* __restrict__ twgT, ushort* __restrict__ twuT,
    ushort* __restrict__ vwgT, ushort* __restrict__ vwuT,
    const float* __restrict__ x, const int* __restrict__ tt,
    const float* __restrict__ t_rw, const float* __restrict__ t_bias,
    const float* __restrict__ v_rw, const float* __restrict__ v_bias,
    int4* __restrict__ ti, float2* __restrict__ tw,
    float* __restrict__ logits_out, ushort* __restrict__ xb) {
  __shared__ uint tile[2][32 * 65];
  int b = blockIdx.x;
  if (b >= PREP_TBLKS) {
    // ---------------- router role ----------------
    int t = (b - PREP_TBLKS) * 4 + (threadIdx.x >> 6);
    int lane = threadIdx.x & 63;
    const float* xr = x + (size_t)t * DIM;
    int vis = tt[t] != 0;
    const float* rw   = vis ? v_rw   : t_rw;
    const float* bias = vis ? v_bias : t_bias;
    float4 xv[4];
#pragma unroll
    for (int i = 0; i < 4; ++i) {
      xv[i] = *(const float4*)(xr + lane * 4 + 256 * i);
      ushort4 o;
      o.x = f2bf(xv[i].x); o.y = f2bf(xv[i].y);
      o.z = f2bf(xv[i].z); o.w = f2bf(xv[i].w);
      *(ushort4*)(xb + (size_t)t * DIM + lane * 4 + 256 * i) = o;
    }
    float lg[8];
#pragma unroll
    for (int e = 0; e < 8; ++e) {
      const float* wrow = rw + (size_t)e * DIM;
      float s = 0.f;
#pragma unroll
      for (int i = 0; i < 4; ++i) {
        float4 wv = *(const float4*)(wrow + lane * 4 + 256 * i);
        s += xv[i].x * wv.x + xv[i].y * wv.y + xv[i].z * wv.z + xv[i].w * wv.w;
      }
#pragma unroll
      for (int off = 32; off > 0; off >>= 1) s += __shfl_xor(s, off);
      lg[e] = s;
    }
    if (lane == 0) {
      float mx = lg[0];
      for (int e = 1; e < 8; ++e) mx = fmaxf(mx, lg[e]);
      float ex[8]; float sum = 0.f;
      for (int e = 0; e < 8; ++e) { ex[e] = __expf(lg[e] - mx); sum += ex[e]; }
      float inv = 1.f / sum;
      float pr[8], sc[8];
      for (int e = 0; e < 8; ++e) { pr[e] = ex[e] * inv; sc[e] = pr[e] + bias[e]; }
      int i0 = 0;
      for (int e = 1; e < 8; ++e) if (sc[e] > sc[i0]) i0 = e;
      int i1 = -1;
      for (int e = 0; e < 8; ++e) {
        if (e == i0) continue;
        if (i1 < 0 || sc[e] > sc[i1]) i1 = e;
      }
      float w0 = pr[i0], w1 = pr[i1];
      float s2 = fmaxf(w0 + w1, 1e-12f);
      w0 /= s2; w1 /= s2;
      ti[t] = make_int4(i0 | (vis << 8), 0, i1, 0);
      tw[t] = make_float2(w0, w1);
      for (int e = 0; e < 8; ++e) logits_out[(size_t)t * 8 + e] = lg[e];
    }
    return;
  }
  // ---------------- wg/wu transpose quarter-slabs ----------------
  // per tensor-expert: 16 kb x 4 quarters = 64 blocks
  const float* src; ushort* dst; int C, kb, q;
  if (b < 128) {                        // shared wg/wu: 2 x 64
    int m = b >> 6; int r = b & 63; kb = r >> 2; q = r & 3;
    src = m ? s_wu : s_wg; dst = m ? swuT : swgT; C = 1024;
  } else if (b < 640) {                 // text wg: 8 x 64
    int i = b - 128; int e = i >> 6; int r = i & 63; kb = r >> 2; q = r & 3;
    src = t_wg + (size_t)e * 524288; dst = twgT + (size_t)e * 524288; C = 512;
  } else if (b < 1152) {                // text wu
    int i = b - 640; int e = i >> 6; int r = i & 63; kb = r >> 2; q = r & 3;
    src = t_wu + (size_t)e * 524288; dst = twuT + (size_t)e * 524288; C = 512;
  } else if (b < 1664) {                // vis wg
    int i = b - 1152; int e = i >> 6; int r = i & 63; kb = r >> 2; q = r & 3;
    src = v_wg + (size_t)e * 262144; dst = vwgT + (size_t)e * 262144; C = 256;
  } else {                              // vis wu
    int i = b - 1664; int e = i >> 6; int r = i & 63; kb = r >> 2; q = r & 3;
    src = v_wu + (size_t)e * 262144; dst = vwuT + (size_t)e * 262144; C = 256;
  }
  int nbq = C >> 8;                     // quarter of C/64
  transpose_slab(src, dst, 1024, C, kb, q * nbq, nbq, tile[0], tile[1]);
}

// ---------------------------------------------------------------------------
// Finalize: ranks via LDS atomics, padded bases, tile->expert maps,
// slot->token lists. One block.
// ---------------------------------------------------------------------------
__global__ __launch_bounds__(256) void finalize_kernel(
    int* __restrict__ meta, int4* __restrict__ ti,
    int* __restrict__ tok_text, int* __restrict__ tok_vis) {
  __shared__ int cnt[16];
  __shared__ int sb[16];
  if (threadIdx.x < 16) cnt[threadIdx.x] = 0;
  __syncthreads();
  for (int t = threadIdx.x; t < 1024; t += 256) {
    int4 v = ti[t];
    int e0 = v.x & 0xff, vis = v.x >> 8, e1 = v.z;
    v.y = atomicAdd(&cnt[vis * 8 + e0], 1);
    v.w = atomicAdd(&cnt[vis * 8 + e1], 1);
    ti[t] = v;
  }
  __syncthreads();
  if (threadIdx.x == 0) {
    int bt = 0, tc = 0;
    for (int e = 0; e < 8; ++e) {
      sb[e] = bt; meta[16 + e] = bt;
      int nt = (cnt[e] + 127) >> 7;
      for (int i = 0; i < nt; ++i) meta[40 + tc++] = e;
      bt += nt << 7;
    }
    meta[34] = bt >> 7;
    int bv = 0, vc = 0;
    for (int e = 0; e < 8; ++e) {
      sb[8 + e] = bv; meta[25 + e] = bv;
      int nt = (cnt[8 + e] + 127) >> 7;
      for (int i = 0; i < nt; ++i) meta[72 + vc++] = e;
      bv += nt << 7;
    }
    meta[35] = bv >> 7;
  }
  __syncthreads();
  for (int i = threadIdx.x; i < MAXSLOT; i += 256) { tok_text[i] = 0; tok_vis[i] = 0; }
  __syncthreads();
  for (int t = threadIdx.x; t < 1024; t += 256) {
    int4 v = ti[t];
    int e0 = v.x & 0xff, vis = v.x >> 8, e1 = v.z;
    int* tl = vis ? tok_vis : tok_text;
    tl[sb[vis * 8 + e0] + v.y] = t;
    tl[sb[vis * 8 + e1] + v.w] = t;
  }
}

// ---------------------------------------------------------------------------
// Up: blocks [0,512): H = silu(Xg@Wg)*(Xg@Wu). BM=128,BN=64,BK=64; dbuf
//     global_load_lds staging with XOR-swizzled sources; swizzled ds_reads.
//     blocks [512,960): wd transpose quarters (grid tail, as in r11).
// ---------------------------------------------------------------------------
__global__ __launch_bounds__(256) void up_kernel(
    const ushort* __restrict__ Xb,
    const ushort* __restrict__ swgT, const ushort* __restrict__ swuT,
    const ushort* __restrict__ twgT, const ushort* __restrict__ twuT,
    const ushort* __restrict__ vwgT, const ushort* __restrict__ vwuT,
    const float* __restrict__ s_wd, const float* __restrict__ t_wd,
    const float* __restrict__ v_wd,
    ushort* __restrict__ swdT, ushort* __restrict__ twdT,
    ushort* __restrict__ vwdT,
    const int* __restrict__ meta,
    const int* __restrict__ tok_text, const int* __restrict__ tok_vis,
    ushort* __restrict__ H_sh, ushort* __restrict__ H_tx,
    ushort* __restrict__ H_vs) {
  __shared__ ushort smem[2][16384];    // 64KB: per buf {A:8192, Bg:4096, Bu:4096}
  int b = blockIdx.x;
  int tid = threadIdx.x, lane = tid & 63, w = tid >> 6;

  if (b >= 512) {                      // -------- wd transpose role --------
    int i = b - 512;
    const float* src; ushort* dst; int K, kb, q;
    if (i < 64) {                      // shared wd: 16 kb x 4
      kb = i >> 2; q = i & 3; src = s_wd; dst = swdT; K = 1024;
    } else if (i < 320) {              // text wd: 8e x 8kb x 4
      int j = i - 64; int e = j >> 5; int r = j & 31; kb = r >> 2; q = r & 3;
      src = t_wd + (size_t)e * 524288; dst = twdT + (size_t)e * 524288; K = 512;
    } else {                           // vis wd: 8e x 4kb x 4
      int j = i - 320; int e = j >> 4; int r = j & 15; kb = r >> 2; q = r & 3;
      src = v_wd + (size_t)e * 262144; dst = vwdT + (size_t)e * 262144; K = 256;
    }
    uint* t0 = (uint*)&smem[0][0];
    uint* t1 = t0 + 32 * 65;
    transpose_slab(src, dst, K, 1024, kb, q * 4, 4, t0, t1);
    return;
  }

  int wm = w >> 1, wn = w & 1;
  int fr = lane & 15, fq = lane >> 4;
  int l8 = lane >> 3, l7 = lane & 7;
  int sw = (l7 ^ l8) * 8;              // XOR-swizzled source slot (halfwords)

  const ushort *Bg, *Bu;               // tile base (this block's 64-wide n tile)
  const int* tl = nullptr;
  ushort* Hout; int hstride, t0, ncol0;
  if (b < 128) {                       // shared experts
    int mt = b >> 4, ng = b & 15;
    t0 = mt * 128; ncol0 = ng * 64;
    Bg = swgT + (size_t)ng * 65536; Bu = swuT + (size_t)ng * 65536;
    Hout = H_sh; hstride = 1024;
  } else if (b < 384) {                // text experts
    int rel = b - 128; int mt = rel >> 3, ng = rel & 7;
    if (mt >= meta[34]) return;
    int e = meta[40 + mt];
    t0 = mt * 128; ncol0 = ng * 64;
    Bg = twgT + (size_t)e * 524288 + (size_t)ng * 65536;
    Bu = twuT + (size_t)e * 524288 + (size_t)ng * 65536;
    tl = tok_text; Hout = H_tx; hstride = 512;
  } else {                             // vision experts
    int rel = b - 384; int mt = rel >> 2, ng = rel & 3;
    if (mt >= meta[35]) return;
    int e = meta[72 + mt];
    t0 = mt * 128; ncol0 = ng * 64;
    Bg = vwgT + (size_t)e * 262144 + (size_t)ng * 65536;
    Bu = vwuT + (size_t)e * 262144 + (size_t)ng * 65536;
    tl = tok_vis; Hout = H_vs; hstride = 256;
  }

  const ushort* aptr[4];
#pragma unroll
  for (int i = 0; i < 4; ++i) {
    int row = (w * 4 + i) * 8 + l8;
    int tok = tl ? tl[t0 + row] : (t0 + row);
    aptr[i] = Xb + (size_t)tok * DIM + sw;
  }
  const ushort *bgp[2], *bup[2];
#pragma unroll
  for (int i = 0; i < 2; ++i) {
    int row = (w * 2 + i) * 8 + l8;   // n_local within 64-wide tile
    bgp[i] = Bg + row * 64 + sw;
    bup[i] = Bu + row * 64 + sw;
  }

  auto stage = [&](int buf, int k0, int koffB) {
    ushort* base = smem[buf];
#pragma unroll
    for (int i = 0; i < 4; ++i)
      gld16(aptr[i] + k0, base + (w * 4 + i) * 512);
#pragma unroll
    for (int i = 0; i < 2; ++i) {
      gld16(bgp[i] + koffB, base + 8192 + (w * 2 + i) * 512);
      gld16(bup[i] + koffB, base + 12288 + (w * 2 + i) * 512);
    }
  };

  f32x4 accg[4][2] = {}; f32x4 accu[4][2] = {};
  int sl[2] = { ((0 * 4 + fq) ^ (fr & 7)) * 8, ((1 * 4 + fq) ^ (fr & 7)) * 8 };

  stage(0, 0, 0);
  __syncthreads();
  for (int t = 0; t < 16; ++t) {
    int cur = t & 1;
    if (t < 15) stage(cur ^ 1, (t + 1) * 64, (t + 1) * 4096);
    const ushort* pA = smem[cur];
    const ushort* pBg = smem[cur] + 8192;
    const ushort* pBu = smem[cur] + 12288;
#pragma unroll
    for (int kk = 0; kk < 2; ++kk) {
      bf16x8 a[4], bg[2], bu[2];
#pragma unroll
      for (int m = 0; m < 4; ++m)
        a[m] = *(const bf16x8*)&pA[(wm * 64 + m * 16 + fr) * 64 + sl[kk]];
#pragma unroll
      for (int n = 0; n < 2; ++n) {
        bg[n] = *(const bf16x8*)&pBg[(wn * 32 + n * 16 + fr) * 64 + sl[kk]];
        bu[n] = *(const bf16x8*)&pBu[(wn * 32 + n * 16 + fr) * 64 + sl[kk]];
      }
#pragma unroll
      for (int m = 0; m < 4; ++m)
#pragma unroll
        for (int n = 0; n < 2; ++n) {
          accg[m][n] = __builtin_amdgcn_mfma_f32_16x16x32_bf16(a[m], bg[n], accg[m][n], 0, 0, 0);
          accu[m][n] = __builtin_amdgcn_mfma_f32_16x16x32_bf16(a[m], bu[n], accu[m][n], 0, 0, 0);
        }
    }
    __syncthreads();
  }

#pragma unroll
  for (int m = 0; m < 4; ++m) {
    int rb = t0 + wm * 64 + m * 16 + fq * 4;
#pragma unroll
    for (int n = 0; n < 2; ++n) {
      int col = ncol0 + wn * 32 + n * 16 + fr;
#pragma unroll
      for (int r = 0; r < 4; ++r) {
        float g = accg[m][n][r], u = accu[m][n][r];
        float h = g / (1.f + __expf(-g)) * u;
        Hout[(size_t)(rb + r) * hstride + col] = f2bf(h);
      }
    }
  }
}

// ---------------------------------------------------------------------------
// Down: shared -> out directly; routed -> pd[slot][1024]. BM=BN=128, BK=64;
// dbuf staging with XOR-swizzled sources + swizzled ds_reads.
// ---------------------------------------------------------------------------
__global__ __launch_bounds__(256) void down_kernel(
    const ushort* __restrict__ H_sh, const ushort* __restrict__ H_tx,
    const ushort* __restrict__ H_vs,
    const ushort* __restrict__ swdT, const ushort* __restrict__ twdT,
    const ushort* __restrict__ vwdT,
    const int* __restrict__ meta, float* __restrict__ out,
    float* __restrict__ pd_tx, float* __restrict__ pd_vs) {
  __shared__ ushort smem[2][16384];    // 64KB: per buf {A:8192, B:8192}
  int b = blockIdx.x;
  int tid = threadIdx.x, lane = tid & 63, w = tid >> 6;
  int wm = w >> 1, wn = w & 1;
  int fr = lane & 15, fq = lane >> 4;
  int l8 = lane >> 3, l7 = lane & 7;
  int sw = (l7 ^ l8) * 8;

  const ushort *A, *Bt; float* O;
  int ksteps, astride, t0, n0;
  if (b < 64) {                        // shared
    int mt = b >> 3, nt = b & 7;
    t0 = mt * 128; n0 = nt * 128;
    A = H_sh; astride = 1024; Bt = swdT; ksteps = 16;
    O = out;
  } else if (b < 320) {                // text
    int rel = b - 64; int mt = rel >> 3, nt = rel & 7;
    if (mt >= meta[34]) return;
    int e = meta[40 + mt];
    t0 = mt * 128; n0 = nt * 128;
    A = H_tx; astride = 512;
    Bt = twdT + (size_t)e * 524288; ksteps = 8;
    O = pd_tx;
  } else {                             // vision
    int rel = b - 320; int mt = rel >> 3, nt = rel & 7;
    if (mt >= meta[35]) return;
    int e = meta[72 + mt];
    t0 = mt * 128; n0 = nt * 128;
    A = H_vs; astride = 256;
    Bt = vwdT + (size_t)e * 262144; ksteps = 4;
    O = pd_vs;
  }

  const ushort *aptr[4], *bptr[4];
#pragma unroll
  for (int i = 0; i < 4; ++i) {
    int c = w * 4 + i;                 // chunk: rows c*8..c*8+7 of 128-row tiles
    int row = c * 8 + l8;
    aptr[i] = A + (size_t)(t0 + row) * astride + sw;
    int nb = (n0 >> 6) + (c >> 3);     // 64-wide n-tile index
    int rowin = row & 63;
    bptr[i] = Bt + (size_t)nb * ksteps * 4096 + rowin * 64 + sw;
  }

  auto stage = [&](int buf, int k0, int koffB) {
    ushort* base = smem[buf];
#pragma unroll
    for (int i = 0; i < 4; ++i) {
      gld16(aptr[i] + k0, base + (w * 4 + i) * 512);
      gld16(bptr[i] + koffB, base + 8192 + (w * 4 + i) * 512);
    }
  };

  f32x4 acc[4][4] = {};
  int sl[2] = { ((0 * 4 + fq) ^ (fr & 7)) * 8, ((1 * 4 + fq) ^ (fr & 7)) * 8 };

  stage(0, 0, 0);
  __syncthreads();
  for (int t = 0; t < ksteps; ++t) {
    int cur = t & 1;
    if (t + 1 < ksteps) stage(cur ^ 1, (t + 1) * 64, (t + 1) * 4096);
    const ushort* pA = smem[cur];
    const ushort* pB = smem[cur] + 8192;
#pragma unroll
    for (int kk = 0; kk < 2; ++kk) {
      bf16x8 a[4], bb[4];
#pragma unroll
      for (int m = 0; m < 4; ++m)
        a[m] = *(const bf16x8*)&pA[(wm * 64 + m * 16 + fr) * 64 + sl[kk]];
#pragma unroll
      for (int n = 0; n < 4; ++n)
        bb[n] = *(const bf16x8*)&pB[(wn * 64 + n * 16 + fr) * 64 + sl[kk]];
#pragma unroll
      for (int m = 0; m < 4; ++m)
#pragma unroll
        for (int n = 0; n < 4; ++n)
          acc[m][n] = __builtin_amdgcn_mfma_f32_16x16x32_bf16(a[m], bb[n], acc[m][n], 0, 0, 0);
    }
    __syncthreads();
  }

#pragma unroll
  for (int m = 0; m < 4; ++m)
#pragma unroll
    for (int n = 0; n < 4; ++n)
#pragma unroll
      for (int r = 0; r < 4; ++r)
        O[(size_t)(t0 + wm * 64 + m * 16 + fq * 4 + r) * DIM
          + n0 + wn * 64 + n * 16 + fr] = acc[m][n][r];
}

// ---------------------------------------------------------------------------
// Combine: out[t] += w0 * pd[slot0] + w1 * pd[slot1]
// ---------------------------------------------------------------------------
__global__ __launch_bounds__(256) void combine_kernel(
    const int4* __restrict__ ti, const float2* __restrict__ tw,
    const int* __restrict__ meta,
    const float* __restrict__ pd_tx, const float* __restrict__ pd_vs,
    float* __restrict__ out) {
  int t = blockIdx.x;
  int4 v = ti[t]; float2 wv = tw[t];
  int e0 = v.x & 0xff, vis = v.x >> 8, e1 = v.z;
  const int* base = meta + (vis ? 25 : 16);
  const float* pd = vis ? pd_vs : pd_tx;
  size_t s0 = base[e0] + v.y, s1 = base[e1] + v.w;
  int d = threadIdx.x * 4;
  f32x4 a  = *(const f32x4*)(out + (size_t)t * DIM + d);
  f32x4 p0 = *(const f32x4*)(pd + s0 * DIM + d);
  f32x4 p1 = *(const f32x4*)(pd + s1 * DIM + d);
#pragma unroll
  for (int j = 0; j < 4; ++j) a[j] = a[j] + wv.x * p0[j] + wv.y * p1[j];
  *(f32x4*)(out + (size_t)t * DIM + d) = a;
}

// ---------------------------------------------------------------------------
extern "C" void kernel_launch(void* const* d_in, const int* in_sizes, int n_in,
                              void* d_out, int out_size, void* d_ws, size_t ws_size,
                              hipStream_t stream) {
  const float* x    = (const float*)d_in[0];
  const int*   tt   = (const int*)d_in[1];
  const float* t_rw = (const float*)d_in[2];
  const float* t_b  = (const float*)d_in[3];
  const float* t_wg = (const float*)d_in[4];
  const float* t_wu = (const float*)d_in[5];
  const float* t_wd = (const float*)d_in[6];
  const float* v_rw = (const float*)d_in[7];
  const float* v_b  = (const float*)d_in[8];
  const float* v_wg = (const float*)d_in[9];
  const float* v_wu = (const float*)d_in[10];
  const float* v_wd = (const float*)d_in[11];
  const float* s_wg = (const float*)d_in[12];
  const float* s_wu = (const float*)d_in[13];
  const float* s_wd = (const float*)d_in[14];
  float* out    = (float*)d_out;
  float* logits = out + (size_t)1024 * 1024;

  char* p = (char*)d_ws;
  auto alloc = [&](size_t bytes) {
    char* r = p; p += (bytes + 255) & ~(size_t)255; return r;
  };
  ushort* xb     = (ushort*)alloc((size_t)1024 * 1024 * 2);
  int4*   ti     = (int4*)alloc((size_t)1024 * 16);
  float2* tw     = (float2*)alloc((size_t)1024 * 8);
  int*    meta   = (int*)alloc(512 * 4);
  int*    tok_tx = (int*)alloc(MAXSLOT * 4);
  int*    tok_vs = (int*)alloc(MAXSLOT * 4);
  ushort* swdT   = (ushort*)alloc((size_t)1024 * 1024 * 2);
  ushort* twdT   = (ushort*)alloc((size_t)8 * 1024 * 512 * 2);
  ushort* vwdT   = (ushort*)alloc((size_t)8 * 1024 * 256 * 2);
  ushort* H_sh   = (ushort*)alloc((size_t)1024 * 1024 * 2);
  ushort* H_tx   = (ushort*)alloc((size_t)MAXSLOT * 512 * 2);
  ushort* H_vs   = (ushort*)alloc((size_t)MAXSLOT * 256 * 2);
  // union region: up-only weights (28MB) overlaid later by pd buffers (32MB)
  char* upmark = p;
  ushort* swgT   = (ushort*)alloc((size_t)1024 * 1024 * 2);
  ushort* swuT   = (ushort*)alloc((size_t)1024 * 1024 * 2);
  ushort* twgT   = (ushort*)alloc((size_t)8 * 512 * 1024 * 2);
  ushort* twuT   = (ushort*)alloc((size_t)8 * 512 * 1024 * 2);
  ushort* vwgT   = (ushort*)alloc((size_t)8 * 256 * 1024 * 2);
  ushort* vwuT   = (ushort*)alloc((size_t)8 * 256 * 1024 * 2);
  float* pd_tx = (float*)upmark;                       // 16 MB
  float* pd_vs = (float*)(upmark + (size_t)MAXSLOT * DIM * 4);  // 16 MB

  prep_router_kernel<<<PREP_TBLKS + 256, 256, 0, stream>>>(
      s_wg, s_wu, t_wg, t_wu, v_wg, v_wu,
      swgT, swuT, twgT, twuT, vwgT, vwuT,
      x, tt, t_rw, t_b, v_rw, v_b, ti, tw, logits, xb);
  finalize_kernel<<<1, 256, 0, stream>>>(meta, ti, tok_tx, tok_vs);
  up_kernel<<<960, 256, 0, stream>>>(xb, swgT, swuT, twgT, twuT, vwgT, vwuT,
                                     s_wd, t_wd, v_wd, swdT, twdT, vwdT,
                                     meta, tok_tx, tok_vs, H_sh, H_tx, H_vs);
  down_kernel<<<576, 256, 0, stream>>>(H_sh, H_tx, H_vs, swdT, twdT, vwdT,
                                       meta, out, pd_tx, pd_vs);
  combine_kernel<<<1024, 256, 0, stream>>>(ti, tw, meta, pd_tx, pd_vs, out);
}

// Round 15
// 70.668 us; speedup vs baseline: 1.1342x; 1.0246x over previous
//
#include <hip/hip_runtime.h>

typedef short bf16x8 __attribute__((ext_vector_type(8)));
typedef float f32x4 __attribute__((ext_vector_type(4)));
typedef ushort ushort8 __attribute__((ext_vector_type(8)));

#define DIM 1024
#define MAXSLOT 4096
#define PREP_TBLKS 1088   // transpose blocks in prep kernel (wg/wu, split x2)

__device__ __forceinline__ ushort f2bf(float f) {
  unsigned u = __float_as_uint(f);
  u += 0x7fffu + ((u >> 16) & 1u);   // round-to-nearest-even
  return (ushort)(u >> 16);
}

__device__ __forceinline__ void gld16(const ushort* g, ushort* l) {
  __builtin_amdgcn_global_load_lds(
      (const __attribute__((address_space(1))) unsigned int*)g,
      (__attribute__((address_space(3))) unsigned int*)l, 16, 0, 0);
}

// ---------------------------------------------------------------------------
// Transpose a sub-range of one 64-row slab of fp32 [K][C] into tiled bf16
// T[C/64][K/64][64][64] (tile [n_local][k_local], 8KB contiguous per tile).
// bf16-PAIR-PACKED LDS tile (8.3KB/buf, dbuf -> full wave occupancy).
// ---------------------------------------------------------------------------
__device__ __forceinline__ void transpose_slab(
    const float* __restrict__ src, ushort* __restrict__ dst,
    int K, int C, int kb, int nb0, int nbcnt, uint* tile0, uint* tile1) {
  int k0 = kb << 6;
  int tid = threadIdx.x;
  int tx = tid & 15, ty = tid >> 4;   // load: cols 4tx.., pair-rows {ty, 16+ty}
  int sx = tid & 7,  sy = tid >> 3;   // store: out rows {sy, 32+sy}, ks 8sx..
  int kt = K >> 6;
  uint* bufs[2] = {tile0, tile1};
  float4 v[4];                        // [p*2+q]: row 2*(p*16+ty)+q

  auto loadT = [&](int nb) {
#pragma unroll
    for (int p = 0; p < 2; ++p)
#pragma unroll
      for (int q = 0; q < 2; ++q)
        v[p * 2 + q] = *(const float4*)(
            src + (size_t)(k0 + (p * 16 + ty) * 2 + q) * C + (nb << 6) + tx * 4);
  };
  auto packW = [&](uint* buf) {
#pragma unroll
    for (int p = 0; p < 2; ++p) {
      uint u[4];
#pragma unroll
      for (int c = 0; c < 4; ++c) {
        float lo = ((const float*)&v[p * 2])[c];
        float hi = ((const float*)&v[p * 2 + 1])[c];
        u[c] = (uint)f2bf(lo) | ((uint)f2bf(hi) << 16);
      }
      *(uint4*)&buf[(p * 16 + ty) * 65 + tx * 4] = *(uint4*)u;
    }
  };

  loadT(nb0); packW(bufs[0]);
  __syncthreads();
  for (int i = 0; i < nbcnt; ++i) {
    bool more = i + 1 < nbcnt;
    if (more) loadT(nb0 + i + 1);
    uint* cur = bufs[i & 1];
    ushort* tb = dst + ((size_t)(nb0 + i) * kt + kb) * 4096;
#pragma unroll
    for (int p = 0; p < 2; ++p) {
      int n = p * 32 + sy;
      ushort8 o;
#pragma unroll
      for (int jj = 0; jj < 4; ++jj) {
        uint u = cur[(4 * sx + jj) * 65 + n];
        o[2 * jj]     = (ushort)(u & 0xffff);
        o[2 * jj + 1] = (ushort)(u >> 16);
      }
      *(ushort8*)(tb + n * 64 + sx * 8) = o;
    }
    if (more) packW(bufs[(i + 1) & 1]);
    __syncthreads();
  }
}

// meta layout (ints): [16..23] base_text; [25..32] base_vis; [34] ntiles_text;
// [35] ntiles_vis; [40..71] tile_expert_text; [72..103] tile_expert_vis.

// ---------------------------------------------------------------------------
// Fused: blocks [0,1088): wg/wu transpose half-slabs. blocks [1088,1344): router.
// ---------------------------------------------------------------------------
__global__ __launch_bounds__(256) void prep_router_kernel(
    const float* __restrict__ s_wg, const float* __restrict__ s_wu,
    const float* __restrict__ t_wg, const float* __restrict__ t_wu,
    const float* __restrict__ v_wg, const float* __restrict__ v_wu,
    ushort* __restrict__ swgT, ushort* __restrict__ swuT,
    ushort* __restrict__ twgT, ushort* __restrict__ twuT,
    ushort* __restrict__ vwgT, ushort* __restrict__ vwuT,
    const float* __restrict__ x, const int* __restrict__ tt,
    const float* __restrict__ t_rw, const float* __restrict__ t_bias,
    const float* __restrict__ v_rw, const float* __restrict__ v_bias,
    int4* __restrict__ ti, float2* __restrict__ tw,
    float* __restrict__ logits_out, ushort* __restrict__ xb) {
  __shared__ uint tile[2][32 * 65];
  int b = blockIdx.x;
  if (b >= PREP_TBLKS) {
    // ---------------- router role ----------------
    int t = (b - PREP_TBLKS) * 4 + (threadIdx.x >> 6);
    int lane = threadIdx.x & 63;
    const float* xr = x + (size_t)t * DIM;
    int vis = tt[t] != 0;
    const float* rw   = vis ? v_rw   : t_rw;
    const float* bias = vis ? v_bias : t_bias;
    float4 xv[4];
#pragma unroll
    for (int i = 0; i < 4; ++i) {
      xv[i] = *(const float4*)(xr + lane * 4 + 256 * i);
      ushort4 o;
      o.x = f2bf(xv[i].x); o.y = f2bf(xv[i].y);
      o.z = f2bf(xv[i].z); o.w = f2bf(xv[i].w);
      *(ushort4*)(xb + (size_t)t * DIM + lane * 4 + 256 * i) = o;
    }
    float lg[8];
#pragma unroll
    for (int e = 0; e < 8; ++e) {
      const float* wrow = rw + (size_t)e * DIM;
      float s = 0.f;
#pragma unroll
      for (int i = 0; i < 4; ++i) {
        float4 wv = *(const float4*)(wrow + lane * 4 + 256 * i);
        s += xv[i].x * wv.x + xv[i].y * wv.y + xv[i].z * wv.z + xv[i].w * wv.w;
      }
#pragma unroll
      for (int off = 32; off > 0; off >>= 1) s += __shfl_xor(s, off);
      lg[e] = s;
    }
    if (lane == 0) {
      float mx = lg[0];
      for (int e = 1; e < 8; ++e) mx = fmaxf(mx, lg[e]);
      float ex[8]; float sum = 0.f;
      for (int e = 0; e < 8; ++e) { ex[e] = __expf(lg[e] - mx); sum += ex[e]; }
      float inv = 1.f / sum;
      float pr[8], sc[8];
      for (int e = 0; e < 8; ++e) { pr[e] = ex[e] * inv; sc[e] = pr[e] + bias[e]; }
      int i0 = 0;
      for (int e = 1; e < 8; ++e) if (sc[e] > sc[i0]) i0 = e;
      int i1 = -1;
      for (int e = 0; e < 8; ++e) {
        if (e == i0) continue;
        if (i1 < 0 || sc[e] > sc[i1]) i1 = e;
      }
      float w0 = pr[i0], w1 = pr[i1];
      float s2 = fmaxf(w0 + w1, 1e-12f);
      w0 /= s2; w1 /= s2;
      ti[t] = make_int4(i0 | (vis << 8), 0, i1, 0);
      tw[t] = make_float2(w0, w1);
      for (int e = 0; e < 8; ++e) logits_out[(size_t)t * 8 + e] = lg[e];
    }
    return;
  }
  // ---------------- wg/wu transpose half-slabs ----------------
  const float* src; ushort* dst; int K = 1024, C, kb, half;
  if (b < 64) {                         // shared wg/wu: 2 x 16 x 2
    int m = b >> 5; int r = b & 31; kb = r >> 1; half = r & 1;
    src = m ? s_wu : s_wg; dst = m ? swuT : swgT; C = 1024;
  } else if (b < 320) {                 // text wg: 8 x 16 x 2
    int i = b - 64; int e = i >> 5; int r = i & 31; kb = r >> 1; half = r & 1;
    src = t_wg + (size_t)e * 524288; dst = twgT + (size_t)e * 524288; C = 512;
  } else if (b < 576) {                 // text wu
    int i = b - 320; int e = i >> 5; int r = i & 31; kb = r >> 1; half = r & 1;
    src = t_wu + (size_t)e * 524288; dst = twuT + (size_t)e * 524288; C = 512;
  } else if (b < 832) {                 // vis wg
    int i = b - 576; int e = i >> 5; int r = i & 31; kb = r >> 1; half = r & 1;
    src = v_wg + (size_t)e * 262144; dst = vwgT + (size_t)e * 262144; C = 256;
  } else {                              // vis wu
    int i = b - 832; int e = i >> 5; int r = i & 31; kb = r >> 1; half = r & 1;
    src = v_wu + (size_t)e * 262144; dst = vwuT + (size_t)e * 262144; C = 256;
  }
  int nbh = C >> 7;                     // half of C/64
  transpose_slab(src, dst, K, C, kb, half * nbh, nbh, tile[0], tile[1]);
}

// ---------------------------------------------------------------------------
// Finalize: ranks via LDS atomics, padded bases, tile->expert maps,
// slot->token lists. One block.
// ---------------------------------------------------------------------------
__global__ __launch_bounds__(256) void finalize_kernel(
    int* __restrict__ meta, int4* __restrict__ ti,
    int* __restrict__ tok_text, int* __restrict__ tok_vis) {
  __shared__ int cnt[16];
  __shared__ int sb[16];
  if (threadIdx.x < 16) cnt[threadIdx.x] = 0;
  __syncthreads();
  for (int t = threadIdx.x; t < 1024; t += 256) {
    int4 v = ti[t];
    int e0 = v.x & 0xff, vis = v.x >> 8, e1 = v.z;
    v.y = atomicAdd(&cnt[vis * 8 + e0], 1);
    v.w = atomicAdd(&cnt[vis * 8 + e1], 1);
    ti[t] = v;
  }
  __syncthreads();
  if (threadIdx.x == 0) {
    int bt = 0, tc = 0;
    for (int e = 0; e < 8; ++e) {
      sb[e] = bt; meta[16 + e] = bt;
      int nt = (cnt[e] + 127) >> 7;
      for (int i = 0; i < nt; ++i) meta[40 + tc++] = e;
      bt += nt << 7;
    }
    meta[34] = bt >> 7;
    int bv = 0, vc = 0;
    for (int e = 0; e < 8; ++e) {
      sb[8 + e] = bv; meta[25 + e] = bv;
      int nt = (cnt[8 + e] + 127) >> 7;
      for (int i = 0; i < nt; ++i) meta[72 + vc++] = e;
      bv += nt << 7;
    }
    meta[35] = bv >> 7;
  }
  __syncthreads();
  for (int i = threadIdx.x; i < MAXSLOT; i += 256) { tok_text[i] = 0; tok_vis[i] = 0; }
  __syncthreads();
  for (int t = threadIdx.x; t < 1024; t += 256) {
    int4 v = ti[t];
    int e0 = v.x & 0xff, vis = v.x >> 8, e1 = v.z;
    int* tl = vis ? tok_vis : tok_text;
    tl[sb[vis * 8 + e0] + v.y] = t;
    tl[sb[vis * 8 + e1] + v.w] = t;
  }
}

// ---------------------------------------------------------------------------
// Up: blocks [0,512): H = silu(Xg@Wg)*(Xg@Wu). BM=128,BN=64,BK=64; dbuf
//     global_load_lds staging with XOR-swizzled sources; swizzled ds_reads.
//     blocks [512,960): wd transpose quarters.
// ---------------------------------------------------------------------------
__global__ __launch_bounds__(256) void up_kernel(
    const ushort* __restrict__ Xb,
    const ushort* __restrict__ swgT, const ushort* __restrict__ swuT,
    const ushort* __restrict__ twgT, const ushort* __restrict__ twuT,
    const ushort* __restrict__ vwgT, const ushort* __restrict__ vwuT,
    const float* __restrict__ s_wd, const float* __restrict__ t_wd,
    const float* __restrict__ v_wd,
    ushort* __restrict__ swdT, ushort* __restrict__ twdT,
    ushort* __restrict__ vwdT,
    const int* __restrict__ meta,
    const int* __restrict__ tok_text, const int* __restrict__ tok_vis,
    ushort* __restrict__ H_sh, ushort* __restrict__ H_tx,
    ushort* __restrict__ H_vs) {
  __shared__ ushort smem[2][16384];    // 64KB: per buf {A:8192, Bg:4096, Bu:4096}
  int b = blockIdx.x;
  int tid = threadIdx.x, lane = tid & 63, w = tid >> 6;

  if (b >= 512) {                      // -------- wd transpose role --------
    int i = b - 512;
    const float* src; ushort* dst; int K, kb, q;
    if (i < 64) {                      // shared wd: 16 kb x 4
      kb = i >> 2; q = i & 3; src = s_wd; dst = swdT; K = 1024;
    } else if (i < 320) {              // text wd: 8e x 8kb x 4
      int j = i - 64; int e = j >> 5; int r = j & 31; kb = r >> 2; q = r & 3;
      src = t_wd + (size_t)e * 524288; dst = twdT + (size_t)e * 524288; K = 512;
    } else {                           // vis wd: 8e x 4kb x 4
      int j = i - 320; int e = j >> 4; int r = j & 15; kb = r >> 2; q = r & 3;
      src = v_wd + (size_t)e * 262144; dst = vwdT + (size_t)e * 262144; K = 256;
    }
    uint* t0 = (uint*)&smem[0][0];
    uint* t1 = t0 + 32 * 65;
    transpose_slab(src, dst, K, 1024, kb, q * 4, 4, t0, t1);
    return;
  }

  int wm = w >> 1, wn = w & 1;
  int fr = lane & 15, fq = lane >> 4;
  int l8 = lane >> 3, l7 = lane & 7;
  int sw = (l7 ^ l8) * 8;              // XOR-swizzled source slot (halfwords)

  const ushort *Bg, *Bu;               // tile base (this block's 64-wide n tile)
  const int* tl = nullptr;
  ushort* Hout; int hstride, t0, ncol0;
  if (b < 128) {                       // shared experts
    int mt = b >> 4, ng = b & 15;
    t0 = mt * 128; ncol0 = ng * 64;
    Bg = swgT + (size_t)ng * 65536; Bu = swuT + (size_t)ng * 65536;
    Hout = H_sh; hstride = 1024;
  } else if (b < 384) {                // text experts
    int rel = b - 128; int mt = rel >> 3, ng = rel & 7;
    if (mt >= meta[34]) return;
    int e = meta[40 + mt];
    t0 = mt * 128; ncol0 = ng * 64;
    Bg = twgT + (size_t)e * 524288 + (size_t)ng * 65536;
    Bu = twuT + (size_t)e * 524288 + (size_t)ng * 65536;
    tl = tok_text; Hout = H_tx; hstride = 512;
  } else {                             // vision experts
    int rel = b - 384; int mt = rel >> 2, ng = rel & 3;
    if (mt >= meta[35]) return;
    int e = meta[72 + mt];
    t0 = mt * 128; ncol0 = ng * 64;
    Bg = vwgT + (size_t)e * 262144 + (size_t)ng * 65536;
    Bu = vwuT + (size_t)e * 262144 + (size_t)ng * 65536;
    tl = tok_vis; Hout = H_vs; hstride = 256;
  }

  const ushort* aptr[4];
#pragma unroll
  for (int i = 0; i < 4; ++i) {
    int row = (w * 4 + i) * 8 + l8;
    int tok = tl ? tl[t0 + row] : (t0 + row);
    aptr[i] = Xb + (size_t)tok * DIM + sw;
  }
  const ushort *bgp[2], *bup[2];
#pragma unroll
  for (int i = 0; i < 2; ++i) {
    int row = (w * 2 + i) * 8 + l8;   // n_local within 64-wide tile
    bgp[i] = Bg + row * 64 + sw;
    bup[i] = Bu + row * 64 + sw;
  }

  auto stage = [&](int buf, int k0, int koffB) {
    ushort* base = smem[buf];
#pragma unroll
    for (int i = 0; i < 4; ++i)
      gld16(aptr[i] + k0, base + (w * 4 + i) * 512);
#pragma unroll
    for (int i = 0; i < 2; ++i) {
      gld16(bgp[i] + koffB, base + 8192 + (w * 2 + i) * 512);
      gld16(bup[i] + koffB, base + 12288 + (w * 2 + i) * 512);
    }
  };

  f32x4 accg[4][2] = {}; f32x4 accu[4][2] = {};
  int sl[2] = { ((0 * 4 + fq) ^ (fr & 7)) * 8, ((1 * 4 + fq) ^ (fr & 7)) * 8 };

  stage(0, 0, 0);
  __syncthreads();
  for (int t = 0; t < 16; ++t) {
    int cur = t & 1;
    if (t < 15) stage(cur ^ 1, (t + 1) * 64, (t + 1) * 4096);
    const ushort* pA = smem[cur];
    const ushort* pBg = smem[cur] + 8192;
    const ushort* pBu = smem[cur] + 12288;
#pragma unroll
    for (int kk = 0; kk < 2; ++kk) {
      bf16x8 a[4], bg[2], bu[2];
#pragma unroll
      for (int m = 0; m < 4; ++m)
        a[m] = *(const bf16x8*)&pA[(wm * 64 + m * 16 + fr) * 64 + sl[kk]];
#pragma unroll
      for (int n = 0; n < 2; ++n) {
        bg[n] = *(const bf16x8*)&pBg[(wn * 32 + n * 16 + fr) * 64 + sl[kk]];
        bu[n] = *(const bf16x8*)&pBu[(wn * 32 + n * 16 + fr) * 64 + sl[kk]];
      }
#pragma unroll
      for (int m = 0; m < 4; ++m)
#pragma unroll
        for (int n = 0; n < 2; ++n) {
          accg[m][n] = __builtin_amdgcn_mfma_f32_16x16x32_bf16(a[m], bg[n], accg[m][n], 0, 0, 0);
          accu[m][n] = __builtin_amdgcn_mfma_f32_16x16x32_bf16(a[m], bu[n], accu[m][n], 0, 0, 0);
        }
    }
    __syncthreads();
  }

#pragma unroll
  for (int m = 0; m < 4; ++m) {
    int rb = t0 + wm * 64 + m * 16 + fq * 4;
#pragma unroll
    for (int n = 0; n < 2; ++n) {
      int col = ncol0 + wn * 32 + n * 16 + fr;
#pragma unroll
      for (int r = 0; r < 4; ++r) {
        float g = accg[m][n][r], u = accu[m][n][r];
        float h = g / (1.f + __expf(-g)) * u;
        Hout[(size_t)(rb + r) * hstride + col] = f2bf(h);
      }
    }
  }
}

// ---------------------------------------------------------------------------
// Down: shared -> out directly; routed -> pd[slot][1024]. BM=BN=128, BK=64;
// dbuf staging with XOR-swizzled sources + swizzled ds_reads.
// ---------------------------------------------------------------------------
__global__ __launch_bounds__(256) void down_kernel(
    const ushort* __restrict__ H_sh, const ushort* __restrict__ H_tx,
    const ushort* __restrict__ H_vs,
    const ushort* __restrict__ swdT, const ushort* __restrict__ twdT,
    const ushort* __restrict__ vwdT,
    const int* __restrict__ meta, float* __restrict__ out,
    float* __restrict__ pd_tx, float* __restrict__ pd_vs) {
  __shared__ ushort smem[2][16384];    // 64KB: per buf {A:8192, B:8192}
  int b = blockIdx.x;
  int tid = threadIdx.x, lane = tid & 63, w = tid >> 6;
  int wm = w >> 1, wn = w & 1;
  int fr = lane & 15, fq = lane >> 4;
  int l8 = lane >> 3, l7 = lane & 7;
  int sw = (l7 ^ l8) * 8;

  const ushort *A, *Bt; float* O;
  int ksteps, astride, t0, n0;
  if (b < 64) {                        // shared
    int mt = b >> 3, nt = b & 7;
    t0 = mt * 128; n0 = nt * 128;
    A = H_sh; astride = 1024; Bt = swdT; ksteps = 16;
    O = out;
  } else if (b < 320) {                // text
    int rel = b - 64; int mt = rel >> 3, nt = rel & 7;
    if (mt >= meta[34]) return;
    int e = meta[40 + mt];
    t0 = mt * 128; n0 = nt * 128;
    A = H_tx; astride = 512;
    Bt = twdT + (size_t)e * 524288; ksteps = 8;
    O = pd_tx;
  } else {                             // vision
    int rel = b - 320; int mt = rel >> 3, nt = rel & 7;
    if (mt >= meta[35]) return;
    int e = meta[72 + mt];
    t0 = mt * 128; n0 = nt * 128;
    A = H_vs; astride = 256;
    Bt = vwdT + (size_t)e * 262144; ksteps = 4;
    O = pd_vs;
  }

  const ushort *aptr[4], *bptr[4];
#pragma unroll
  for (int i = 0; i < 4; ++i) {
    int c = w * 4 + i;                 // chunk: rows c*8..c*8+7 of 128-row tiles
    int row = c * 8 + l8;
    aptr[i] = A + (size_t)(t0 + row) * astride + sw;
    int nb = (n0 >> 6) + (c >> 3);     // 64-wide n-tile index
    int rowin = row & 63;
    bptr[i] = Bt + (size_t)nb * ksteps * 4096 + rowin * 64 + sw;
  }

  auto stage = [&](int buf, int k0, int koffB) {
    ushort* base = smem[buf];
#pragma unroll
    for (int i = 0; i < 4; ++i) {
      gld16(aptr[i] + k0, base + (w * 4 + i) * 512);
      gld16(bptr[i] + koffB, base + 8192 + (w * 4 + i) * 512);
    }
  };

  f32x4 acc[4][4] = {};
  int sl[2] = { ((0 * 4 + fq) ^ (fr & 7)) * 8, ((1 * 4 + fq) ^ (fr & 7)) * 8 };

  stage(0, 0, 0);
  __syncthreads();
  for (int t = 0; t < ksteps; ++t) {
    int cur = t & 1;
    if (t + 1 < ksteps) stage(cur ^ 1, (t + 1) * 64, (t + 1) * 4096);
    const ushort* pA = smem[cur];
    const ushort* pB = smem[cur] + 8192;
#pragma unroll
    for (int kk = 0; kk < 2; ++kk) {
      bf16x8 a[4], bb[4];
#pragma unroll
      for (int m = 0; m < 4; ++m)
        a[m] = *(const bf16x8*)&pA[(wm * 64 + m * 16 + fr) * 64 + sl[kk]];
#pragma unroll
      for (int n = 0; n < 4; ++n)
        bb[n] = *(const bf16x8*)&pB[(wn * 64 + n * 16 + fr) * 64 + sl[kk]];
#pragma unroll
      for (int m = 0; m < 4; ++m)
#pragma unroll
        for (int n = 0; n < 4; ++n)
          acc[m][n] = __builtin_amdgcn_mfma_f32_16x16x32_bf16(a[m], bb[n], acc[m][n], 0, 0, 0);
    }
    __syncthreads();
  }

#pragma unroll
  for (int m = 0; m < 4; ++m)
#pragma unroll
    for (int n = 0; n < 4; ++n)
#pragma unroll
      for (int r = 0; r < 4; ++r)
        O[(size_t)(t0 + wm * 64 + m * 16 + fq * 4 + r) * DIM
          + n0 + wn * 64 + n * 16 + fr] = acc[m][n][r];
}

// ---------------------------------------------------------------------------
// Combine: out[t] += w0 * pd[slot0] + w1 * pd[slot1]
// ---------------------------------------------------------------------------
__global__ __launch_bounds__(256) void combine_kernel(
    const int4* __restrict__ ti, const float2* __restrict__ tw,
    const int* __restrict__ meta,
    const float* __restrict__ pd_tx, const float* __restrict__ pd_vs,
    float* __restrict__ out) {
  int t = blockIdx.x;
  int4 v = ti[t]; float2 wv = tw[t];
  int e0 = v.x & 0xff, vis = v.x >> 8, e1 = v.z;
  const int* base = meta + (vis ? 25 : 16);
  const float* pd = vis ? pd_vs : pd_tx;
  size_t s0 = base[e0] + v.y, s1 = base[e1] + v.w;
  int d = threadIdx.x * 4;
  f32x4 a  = *(const f32x4*)(out + (size_t)t * DIM + d);
  f32x4 p0 = *(const f32x4*)(pd + s0 * DIM + d);
  f32x4 p1 = *(const f32x4*)(pd + s1 * DIM + d);
#pragma unroll
  for (int j = 0; j < 4; ++j) a[j] = a[j] + wv.x * p0[j] + wv.y * p1[j];
  *(f32x4*)(out + (size_t)t * DIM + d) = a;
}

// ---------------------------------------------------------------------------
extern "C" void kernel_launch(void* const* d_in, const int* in_sizes, int n_in,
                              void* d_out, int out_size, void* d_ws, size_t ws_size,
                              hipStream_t stream) {
  const float* x    = (const float*)d_in[0];
  const int*   tt   = (const int*)d_in[1];
  const float* t_rw = (const float*)d_in[2];
  const float* t_b  = (const float*)d_in[3];
  const float* t_wg = (const float*)d_in[4];
  const float* t_wu = (const float*)d_in[5];
  const float* t_wd = (const float*)d_in[6];
  const float* v_rw = (const float*)d_in[7];
  const float* v_b  = (const float*)d_in[8];
  const float* v_wg = (const float*)d_in[9];
  const float* v_wu = (const float*)d_in[10];
  const float* v_wd = (const float*)d_in[11];
  const float* s_wg = (const float*)d_in[12];
  const float* s_wu = (const float*)d_in[13];
  const float* s_wd = (const float*)d_in[14];
  float* out    = (float*)d_out;
  float* logits = out + (size_t)1024 * 1024;

  char* p = (char*)d_ws;
  auto alloc = [&](size_t bytes) {
    char* r = p; p += (bytes + 255) & ~(size_t)255; return r;
  };
  ushort* xb     = (ushort*)alloc((size_t)1024 * 1024 * 2);
  int4*   ti     = (int4*)alloc((size_t)1024 * 16);
  float2* tw     = (float2*)alloc((size_t)1024 * 8);
  int*    meta   = (int*)alloc(512 * 4);
  int*    tok_tx = (int*)alloc(MAXSLOT * 4);
  int*    tok_vs = (int*)alloc(MAXSLOT * 4);
  ushort* swdT   = (ushort*)alloc((size_t)1024 * 1024 * 2);
  ushort* twdT   = (ushort*)alloc((size_t)8 * 1024 * 512 * 2);
  ushort* vwdT   = (ushort*)alloc((size_t)8 * 1024 * 256 * 2);
  ushort* H_sh   = (ushort*)alloc((size_t)1024 * 1024 * 2);
  ushort* H_tx   = (ushort*)alloc((size_t)MAXSLOT * 512 * 2);
  ushort* H_vs   = (ushort*)alloc((size_t)MAXSLOT * 256 * 2);
  // union region: up-only weights (28MB) overlaid later by pd buffers (32MB)
  char* upmark = p;
  ushort* swgT   = (ushort*)alloc((size_t)1024 * 1024 * 2);
  ushort* swuT   = (ushort*)alloc((size_t)1024 * 1024 * 2);
  ushort* twgT   = (ushort*)alloc((size_t)8 * 512 * 1024 * 2);
  ushort* twuT   = (ushort*)alloc((size_t)8 * 512 * 1024 * 2);
  ushort* vwgT   = (ushort*)alloc((size_t)8 * 256 * 1024 * 2);
  ushort* vwuT   = (ushort*)alloc((size_t)8 * 256 * 1024 * 2);
  float* pd_tx = (float*)upmark;                       // 16 MB
  float* pd_vs = (float*)(upmark + (size_t)MAXSLOT * DIM * 4);  // 16 MB

  prep_router_kernel<<<PREP_TBLKS + 256, 256, 0, stream>>>(
      s_wg, s_wu, t_wg, t_wu, v_wg, v_wu,
      swgT, swuT, twgT, twuT, vwgT, vwuT,
      x, tt, t_rw, t_b, v_rw, v_b, ti, tw, logits, xb);
  finalize_kernel<<<1, 256, 0, stream>>>(meta, ti, tok_tx, tok_vs);
  up_kernel<<<960, 256, 0, stream>>>(xb, swgT, swuT, twgT, twuT, vwgT, vwuT,
                                     s_wd, t_wd, v_wd, swdT, twdT, vwdT,
                                     meta, tok_tx, tok_vs, H_sh, H_tx, H_vs);
  down_kernel<<<576, 256, 0, stream>>>(H_sh, H_tx, H_vs, swdT, twdT, vwdT,
                                       meta, out, pd_tx, pd_vs);
  combine_kernel<<<1024, 256, 0, stream>>>(ti, tw, meta, pd_tx, pd_vs, out);
}